// Round 8
// baseline (231.348 us; speedup 1.0000x reference)
//
#include <hip/hip_runtime.h>

#define BB 16
#define SS 2048
#define DD 128
// exp(s/sqrt(128)) = 2^(s * CE),  CE = log2(e)/sqrt(128)
#define CE (0.08838834764831845f * 1.4426950408889634f)

typedef __attribute__((ext_vector_type(4))) float f32x4;
typedef __attribute__((ext_vector_type(8))) short short8;
typedef __attribute__((ext_vector_type(4))) unsigned short us4;
typedef __attribute__((ext_vector_type(8))) unsigned short us8;

__device__ inline unsigned short f2bf(float f) {
    unsigned u = __float_as_uint(f);
    u += 0x7fffu + ((u >> 16) & 1u);   // round-to-nearest-even
    return (unsigned short)(u >> 16);
}

// XOR swizzles (swzA: 256B rows; swzB: 128B rows)
__device__ inline int swzA(int row, int col) {
    int byteoff = (row << 8) + ((col >> 3) << 4);
    byteoff ^= (row & 7) << 4;
    return (byteoff >> 1) + (col & 7);
}
__device__ inline int swzB(int row, int col) {
    int byteoff = (row << 7) + ((col >> 3) << 4);
    byteoff ^= (row & 7) << 4;
    return (byteoff >> 1) + (col & 7);
}

// ---------------------------------------------------------------------------
// prep: Q,K fp32 -> bf16; mask -> additive fp32 (0/-inf); V -> VT bf16.
// grid (S/64, B), 256 thr.
// ---------------------------------------------------------------------------
__global__ __launch_bounds__(256) void prep_kernel(
    const float* __restrict__ Q, const float* __restrict__ K,
    const float* __restrict__ V, const int* __restrict__ mask,
    unsigned short* __restrict__ Qb, unsigned short* __restrict__ Kb,
    unsigned short* __restrict__ VT, float* __restrict__ maskAdd)
{
    __shared__ unsigned short tile[64 * 136];
    int b = blockIdx.y, k0 = blockIdx.x << 6;
    int t = threadIdx.x;
    const size_t base = ((size_t)b * SS + k0) * DD;   // 8192 elements

    for (int i = 0; i < 8; ++i) {
        int f4 = (i << 8) + t;
        f32x4 q = reinterpret_cast<const f32x4*>(Q + base)[f4];
        f32x4 k = reinterpret_cast<const f32x4*>(K + base)[f4];
        us4 qh, kh;
        for (int j = 0; j < 4; ++j) { qh[j] = f2bf(q[j]); kh[j] = f2bf(k[j]); }
        reinterpret_cast<us4*>(Qb + base)[f4] = qh;
        reinterpret_cast<us4*>(Kb + base)[f4] = kh;
    }
    if (t < 64)
        maskAdd[(size_t)b * SS + k0 + t] =
            mask[(size_t)b * SS + k0 + t] ? 0.0f : __int_as_float(0xff800000);

    for (int i = 0; i < 8; ++i) {
        int f4 = (i << 8) + t;
        int k  = f4 >> 5;
        int n  = (f4 & 31) << 2;
        f32x4 v = reinterpret_cast<const f32x4*>(V + base)[f4];
        us4 h;
        for (int j = 0; j < 4; ++j) h[j] = f2bf(v[j]);
        *reinterpret_cast<us4*>(&tile[k * 136 + n]) = h;
    }
    __syncthreads();
    unsigned short* outp = VT + (size_t)b * DD * SS;
    for (int i = 0; i < 4; ++i) {
        int id = (i << 8) + t;
        int n  = id >> 3;
        int c8 = id & 7;
        us8 o;
        for (int j = 0; j < 8; ++j) o[j] = tile[((c8 << 3) + j) * 136 + n];
        *reinterpret_cast<us8*>(&outp[(size_t)n * SS + k0 + (c8 << 3)]) = o;
    }
}

// ---------------------------------------------------------------------------
// flashA: double-buffered, ONE barrier per 64-kv tile; split-k (2 halves) with
// IN-KERNEL combine: second block to finish a (b,qb) pair reads both partials
// and writes final O. grid 512, 256 thr, 2 blocks/CU. 32 q/wave.
// ---------------------------------------------------------------------------
__global__ __launch_bounds__(256, 2) void flashA_kernel(
    const unsigned short* __restrict__ Qb, const unsigned short* __restrict__ Kb,
    const unsigned short* __restrict__ VT, const float* __restrict__ maskAdd,
    float* __restrict__ Op0, float* __restrict__ Op1, float* __restrict__ Lp,
    float* __restrict__ O, int* __restrict__ flags)
{
    __shared__ unsigned short Ks[2][64 * 128];    // 2 x 16 KB
    __shared__ unsigned short VTs[2][128 * 64];   // 2 x 16 KB
    __shared__ unsigned short Ps[4 * 1024];       // per-wave 16q-row x 64col (2 KB)
    __shared__ int sOld;

    const int id = blockIdx.x;
    const int xcd = id & 7, j = id >> 3;
    const int b   = (xcd << 1) | (j >> 5);
    const int rem = j & 31;
    const int half = rem >> 4, qb = rem & 15;
    const int q0 = qb << 7;
    const int kvbase = half << 10;

    const int t = threadIdx.x, lane = t & 63, w = t >> 6;
    const int lr = lane & 15, lg = lane >> 4;

    const unsigned short* Kbb = Kb + (size_t)b * SS * DD;
    const unsigned short* Vbb = VT + (size_t)b * DD * SS;
    const float* Mb = maskAdd + (size_t)b * SS;

    // Q fragments (B-operand): q = q0 + w*32 + m*16 + lr
    const unsigned short* Qp = Qb + ((size_t)b * SS + q0 + w * 32) * DD;
    short8 qf[2][4];
    for (int m = 0; m < 2; ++m)
        for (int kb = 0; kb < 4; ++kb)
            qf[m][kb] = *reinterpret_cast<const short8*>(
                Qp + (size_t)(m * 16 + lr) * DD + kb * 32 + lg * 8);

    f32x4 oacc[2][8] = {};
    float rsum[2] = {0.f, 0.f};
    unsigned short* Pw = &Ps[w * 1024];

    us8 kstg[4], vstg[4];
#define LOADTILE(kv)                                                             \
    for (int i = 0; i < 4; ++i) {                                                \
        int f = i * 256 + t;                                                     \
        kstg[i] = *reinterpret_cast<const us8*>(                                 \
            Kbb + (size_t)((kv) + (f >> 4)) * DD + ((f & 15) << 3));             \
        vstg[i] = *reinterpret_cast<const us8*>(                                 \
            Vbb + (size_t)(f >> 3) * SS + (kv) + ((f & 7) << 3));                \
    }
#define WRITETILE(bf)                                                            \
    for (int i = 0; i < 4; ++i) {                                                \
        int f = i * 256 + t;                                                     \
        *reinterpret_cast<us8*>(&Ks[bf][swzA(f >> 4, (f & 15) << 3)]) = kstg[i]; \
        *reinterpret_cast<us8*>(&VTs[bf][swzB(f >> 3, (f & 7) << 3)]) = vstg[i]; \
    }

    LOADTILE(kvbase);
    WRITETILE(0);

    for (int kt = 0; kt < 16; ++kt) {
        const int cur = kt & 1;
        const int kv0 = kvbase + (kt << 6);
        if (kt + 1 < 16) { LOADTILE(kv0 + 64); }   // T14: latency hides under compute
        __syncthreads();                           // buf[cur] writes visible

        // S^T = K . Q^T  (rows = kv, cols = q) — order identical to pstore
        f32x4 sacc[2][4] = {};
        __builtin_amdgcn_s_setprio(1);
        for (int kb = 0; kb < 4; ++kb) {
            short8 kf[4];
            for (int n = 0; n < 4; ++n)
                kf[n] = *reinterpret_cast<const short8*>(
                    &Ks[cur][swzA(n * 16 + lr, kb * 32 + lg * 8)]);
            for (int n = 0; n < 4; ++n)
                for (int m = 0; m < 2; ++m)
                    sacc[m][n] = __builtin_amdgcn_mfma_f32_16x16x32_bf16(
                        kf[n], qf[m][kb], sacc[m][n], 0, 0, 0);
        }
        __builtin_amdgcn_s_setprio(0);

        // two 32-kv halves: exp -> wave-local P stash -> PV
        for (int h = 0; h < 2; ++h) {
            for (int nl = 0; nl < 2; ++nl) {
                int n = h * 2 + nl;
                f32x4 ma = *reinterpret_cast<const f32x4*>(Mb + kv0 + n * 16 + lg * 4);
                for (int m = 0; m < 2; ++m) {
                    us4 hh;
                    for (int r = 0; r < 4; ++r) {
                        float p = __builtin_amdgcn_exp2f(fmaf(sacc[m][n][r], CE, ma[r]));
                        rsum[m] += p;
                        hh[r] = f2bf(p);
                    }
                    *reinterpret_cast<us4*>(&Pw[swzB(lr, m * 32 + nl * 16 + lg * 4)]) = hh;
                }
            }
            asm volatile("s_waitcnt lgkmcnt(0)" ::: "memory");
            __builtin_amdgcn_sched_barrier(0);

            short8 pf[2];
            for (int m = 0; m < 2; ++m)
                pf[m] = *reinterpret_cast<const short8*>(&Pw[swzB(lr, m * 32 + lg * 8)]);
            __builtin_amdgcn_s_setprio(1);
            for (int nd = 0; nd < 8; ++nd) {
                short8 vf = *reinterpret_cast<const short8*>(
                    &VTs[cur][swzB(nd * 16 + lr, h * 32 + lg * 8)]);
                for (int m = 0; m < 2; ++m)
                    oacc[m][nd] = __builtin_amdgcn_mfma_f32_16x16x32_bf16(
                        pf[m], vf, oacc[m][nd], 0, 0, 0);
            }
            __builtin_amdgcn_s_setprio(0);
        }

        if (kt + 1 < 16) { WRITETILE(cur ^ 1); }   // safe: readers passed barrier above
    }
#undef LOADTILE
#undef WRITETILE

    // reduce L across lg groups; write partial L and unnormalized partial O
    for (int m = 0; m < 2; ++m) {
        rsum[m] += __shfl_xor(rsum[m], 16, 64);
        rsum[m] += __shfl_xor(rsum[m], 32, 64);
    }
    if (lane < 16)
        for (int m = 0; m < 2; ++m)
            Lp[(size_t)half * BB * SS + (size_t)b * SS + q0 + w * 32 + m * 16 + lane] = rsum[m];

    float* Op = half ? Op1 : Op0;
    float* Og = Op + ((size_t)b * SS + q0 + w * 32) * DD;
    for (int m = 0; m < 2; ++m)
        for (int nd = 0; nd < 8; ++nd)
            for (int r = 0; r < 4; ++r)
                Og[(size_t)(m * 16 + lg * 4 + r) * DD + nd * 16 + lr] = oacc[m][nd][r];

    // ---- split-k in-kernel combine: second finisher merges both halves ----
    __threadfence();                  // release: partial O + Lp visible device-wide
    __syncthreads();                  // all threads' stores + fences done
    if (t == 0) sOld = atomicAdd(&flags[b * 16 + qb], 1);
    __syncthreads();
    if (sOld == 1) {
        __threadfence();              // acquire: other block's partials visible
        const f32x4* PA = reinterpret_cast<const f32x4*>(Op0 + ((size_t)b * SS + q0) * DD);
        const f32x4* PB = reinterpret_cast<const f32x4*>(Op1 + ((size_t)b * SS + q0) * DD);
        f32x4* Of = reinterpret_cast<f32x4*>(O + ((size_t)b * SS + q0) * DD);
        const float* L0 = Lp + (size_t)b * SS + q0;
        const float* L1 = Lp + (size_t)BB * SS + (size_t)b * SS + q0;
        for (int i = 0; i < 16; ++i) {
            int idx = i * 256 + t;    // 4096 f32x4 in the 128x128 block
            int row = idx >> 5;       // 32 f32x4 per row
            float L = L0[row] + L1[row];
            float il = L > 0.f ? 1.f / L : 0.f;
            f32x4 a = PA[idx], c = PB[idx];
            f32x4 o;
            for (int r = 0; r < 4; ++r) o[r] = (a[r] + c[r]) * il;
            Of[idx] = o;
        }
    }
}

// ---------------------------------------------------------------------------
// pstore: double-buffered K staging, ONE barrier per tile. Computes its own
// log2(1/L) from Lp. Recomputes S^T bit-identically, writes
// P = 2^(s*CE + maskAdd + lil). grid 1024 (kv-split 4), 256 thr, 4 blocks/CU.
// ---------------------------------------------------------------------------
__global__ __launch_bounds__(256, 4) void pstore_kernel(
    const unsigned short* __restrict__ Qb, const unsigned short* __restrict__ Kb,
    const float* __restrict__ maskAdd, const float* __restrict__ Lp,
    float* __restrict__ P)
{
    __shared__ unsigned short Ks[2][64 * 128];

    const int id = blockIdx.x;
    const int xcd = id & 7, j = id >> 3;          // grid 1024
    const int b   = (xcd << 1) | (j >> 6);
    const int rem = j & 63;
    const int kvq = rem >> 4, qb = rem & 15;
    const int q0 = qb << 7, kvbase = kvq << 9;

    const int t = threadIdx.x, lane = t & 63, w = t >> 6;
    const int lr = lane & 15, lg = lane >> 4;

    const unsigned short* Kbb = Kb + (size_t)b * SS * DD;
    const float* Mb = maskAdd + (size_t)b * SS;

    const unsigned short* Qp = Qb + ((size_t)b * SS + q0 + w * 32) * DD;
    short8 qf[2][4];
    for (int m = 0; m < 2; ++m)
        for (int kb = 0; kb < 4; ++kb)
            qf[m][kb] = *reinterpret_cast<const short8*>(
                Qp + (size_t)(m * 16 + lr) * DD + kb * 32 + lg * 8);

    float lil[2];
    for (int m = 0; m < 2; ++m) {
        size_t rowi = (size_t)b * SS + q0 + w * 32 + m * 16 + lr;
        float L = Lp[rowi] + Lp[(size_t)BB * SS + rowi];
        lil[m] = L > 0.f ? -__builtin_amdgcn_logf(L) : __int_as_float(0xff800000);
    }

    us8 kstg[4];
#define LOADK(kv)                                                                \
    for (int i = 0; i < 4; ++i) {                                                \
        int f = i * 256 + t;                                                     \
        kstg[i] = *reinterpret_cast<const us8*>(                                 \
            Kbb + (size_t)((kv) + (f >> 4)) * DD + ((f & 15) << 3));             \
    }
#define WRITEK(bf)                                                               \
    for (int i = 0; i < 4; ++i) {                                                \
        int f = i * 256 + t;                                                     \
        *reinterpret_cast<us8*>(&Ks[bf][swzA(f >> 4, (f & 15) << 3)]) = kstg[i]; \
    }

    LOADK(kvbase);
    WRITEK(0);

    for (int kt = 0; kt < 8; ++kt) {
        const int cur = kt & 1;
        const int kv0 = kvbase + (kt << 6);
        if (kt + 1 < 8) { LOADK(kv0 + 64); }
        __syncthreads();

        // identical structure/order to flashA -> bit-identical sacc
        f32x4 sacc[2][4] = {};
        for (int kb = 0; kb < 4; ++kb) {
            short8 kf[4];
            for (int n = 0; n < 4; ++n)
                kf[n] = *reinterpret_cast<const short8*>(
                    &Ks[cur][swzA(n * 16 + lr, kb * 32 + lg * 8)]);
            for (int n = 0; n < 4; ++n)
                for (int m = 0; m < 2; ++m)
                    sacc[m][n] = __builtin_amdgcn_mfma_f32_16x16x32_bf16(
                        kf[n], qf[m][kb], sacc[m][n], 0, 0, 0);
        }

        for (int m = 0; m < 2; ++m) {
            float* Pp = P + ((size_t)b * SS + q0 + w * 32 + m * 16 + lr) * SS + kv0;
            for (int n = 0; n < 4; ++n) {
                f32x4 ma = *reinterpret_cast<const f32x4*>(Mb + kv0 + n * 16 + lg * 4);
                f32x4 out;
                for (int r = 0; r < 4; ++r)
                    out[r] = __builtin_amdgcn_exp2f(
                        fmaf(sacc[m][n][r], CE, ma[r]) + lil[m]);
                *reinterpret_cast<f32x4*>(Pp + n * 16 + lg * 4) = out;
            }
        }

        if (kt + 1 < 8) { WRITEK(cur ^ 1); }
    }
#undef LOADK
#undef WRITEK
}

// ---------------------------------------------------------------------------
// Fallback pipeline (no workspace requirements)
// ---------------------------------------------------------------------------
__global__ __launch_bounds__(256) void qk_exp_kernel(
    const float* __restrict__ Q, const float* __restrict__ Kin,
    const int* __restrict__ mask, float* __restrict__ P)
{
    __shared__ unsigned short Qs[128 * 128];
    __shared__ unsigned short Ks[128 * 128];
    const int b  = blockIdx.z;
    const int m0 = blockIdx.y << 7;
    const int n0 = blockIdx.x << 7;
    const int t  = threadIdx.x;
    const float* Qp = Q   + ((size_t)b * SS + m0) * DD;
    const float* Kp = Kin + ((size_t)b * SS + n0) * DD;
    for (int i = 0; i < 16; ++i) {
        int f4  = (i << 8) + t;
        int row = f4 >> 5;
        int col = (f4 & 31) << 2;
        f32x4 q = reinterpret_cast<const f32x4*>(Qp)[f4];
        f32x4 k = reinterpret_cast<const f32x4*>(Kp)[f4];
        us4 qh, kh;
        for (int jj = 0; jj < 4; ++jj) { qh[jj] = f2bf(q[jj]); kh[jj] = f2bf(k[jj]); }
        *reinterpret_cast<us4*>(&Qs[swzA(row, col)]) = qh;
        *reinterpret_cast<us4*>(&Ks[swzA(row, col)]) = kh;
    }
    __syncthreads();
    const int lane = t & 63, wid = t >> 6;
    const int wr = wid >> 1, wc = wid & 1;
    const int lr = lane & 15, lg = lane >> 4;
    f32x4 acc[4][4] = {};
    for (int kb = 0; kb < 4; ++kb) {
        short8 a[4], bq[4];
        int kcol = (kb << 5) + (lg << 3);
        for (int m = 0; m < 4; ++m)
            a[m] = *reinterpret_cast<const short8*>(&Qs[swzA((wr << 6) + (m << 4) + lr, kcol)]);
        for (int n = 0; n < 4; ++n)
            bq[n] = *reinterpret_cast<const short8*>(&Ks[swzA((wc << 6) + (n << 4) + lr, kcol)]);
        for (int m = 0; m < 4; ++m)
            for (int n = 0; n < 4; ++n)
                acc[m][n] = __builtin_amdgcn_mfma_f32_16x16x32_bf16(a[m], bq[n], acc[m][n], 0, 0, 0);
    }
    const int* am = mask + (size_t)b * SS;
    for (int n = 0; n < 4; ++n) {
        int col = n0 + (wc << 6) + (n << 4) + lr;
        bool allow = am[col] != 0;
        for (int m = 0; m < 4; ++m) {
            int rowb = m0 + (wr << 6) + (m << 4) + (lg << 2);
            float* Pp = P + ((size_t)b * SS + rowb) * SS + col;
            for (int r = 0; r < 4; ++r) {
                float p = allow ? __expf(acc[m][n][r] * 0.08838834764831845f) : 0.0f;
                Pp[(size_t)r * SS] = p;
            }
        }
    }
}

__global__ __launch_bounds__(256) void norm_kernel(float* __restrict__ P)
{
    int row  = (blockIdx.x << 2) + (threadIdx.x >> 6);
    int lane = threadIdx.x & 63;
    float* Pr = P + (size_t)row * SS;
    f32x4 v[8];
    float sum = 0.f;
    for (int i = 0; i < 8; ++i) {
        v[i] = reinterpret_cast<f32x4*>(Pr)[(i << 6) + lane];
        sum += v[i][0] + v[i][1] + v[i][2] + v[i][3];
    }
    for (int off = 1; off < 64; off <<= 1) sum += __shfl_xor(sum, off, 64);
    float inv = sum > 0.f ? 1.f / sum : 0.f;
    for (int i = 0; i < 8; ++i) {
        f32x4 wv = v[i];
        for (int jj = 0; jj < 4; ++jj) wv[jj] *= inv;
        reinterpret_cast<f32x4*>(Pr)[(i << 6) + lane] = wv;
    }
}

__global__ __launch_bounds__(256) void pv_fallback_kernel(
    const float* __restrict__ P, const float* __restrict__ V, float* __restrict__ O)
{
    __shared__ unsigned short Ws[64 * 64];
    const int b  = blockIdx.y;
    const int m0 = blockIdx.x << 6;
    const int t  = threadIdx.x, lane = t & 63, wid = t >> 6;
    const int wr = wid >> 1, wc = wid & 1;
    const int lr = lane & 15, lg = lane >> 4;
    const float* Pg = P + ((size_t)b * SS + m0) * SS;
    f32x4 acc[2][4] = {};
    for (int k0 = 0; k0 < SS; k0 += 64) {
        __syncthreads();
        for (int i = 0; i < 4; ++i) {
            int f4  = (i << 8) + t;
            int row = f4 >> 4;
            int col = (f4 & 15) << 2;
            f32x4 wv = *reinterpret_cast<const f32x4*>(Pg + (size_t)row * SS + k0 + col);
            us4 h;
            for (int jj = 0; jj < 4; ++jj) h[jj] = f2bf(wv[jj]);
            *reinterpret_cast<us4*>(&Ws[swzB(row, col)]) = h;
        }
        __syncthreads();
        for (int kk = 0; kk < 64; kk += 32) {
            short8 a[2], bv[4];
            int kcol = kk + (lg << 3);
            for (int m = 0; m < 2; ++m)
                a[m] = *reinterpret_cast<const short8*>(&Ws[swzB((wr << 5) + (m << 4) + lr, kcol)]);
            for (int n = 0; n < 4; ++n) {
                int col = (wc << 6) + (n << 4) + lr;
                const float* vp = V + ((size_t)b * SS + k0 + kcol) * DD + col;
                short8 x;
                for (int jj = 0; jj < 8; ++jj) x[jj] = (short)f2bf(vp[(size_t)jj * DD]);
                bv[n] = x;
            }
            for (int m = 0; m < 2; ++m)
                for (int n = 0; n < 4; ++n)
                    acc[m][n] = __builtin_amdgcn_mfma_f32_16x16x32_bf16(a[m], bv[n], acc[m][n], 0, 0, 0);
        }
    }
    float* Og = O + ((size_t)b * SS + m0) * DD;
    for (int m = 0; m < 2; ++m)
        for (int n = 0; n < 4; ++n)
            for (int r = 0; r < 4; ++r)
                Og[(size_t)((wr << 5) + (m << 4) + (lg << 2) + r) * DD
                   + (wc << 6) + (n << 4) + lr] = acc[m][n][r];
}

// ---------------------------------------------------------------------------
extern "C" void kernel_launch(void* const* d_in, const int* in_sizes, int n_in,
                              void* d_out, int out_size, void* d_ws, size_t ws_size,
                              hipStream_t stream)
{
    const float* Q  = (const float*)d_in[0];
    const float* K  = (const float*)d_in[1];
    const float* V  = (const float*)d_in[2];
    const int* mask = (const int*)d_in[3];
    float* O = (float*)d_out;
    float* P = O + (size_t)BB * SS * DD;

    const size_t nE = (size_t)BB * SS * DD;   // 4194304 elements per tensor
    const size_t need = 3 * nE * sizeof(unsigned short)
                      + 3 * (size_t)BB * SS * sizeof(float)
                      + 256 * sizeof(int) + 256;

    if (ws_size >= need) {
        unsigned short* Qb = (unsigned short*)d_ws;
        unsigned short* Kb = Qb + nE;
        unsigned short* VT = Kb + nE;
        float* maskAdd = (float*)(VT + nE);
        float* Lp      = maskAdd + (size_t)BB * SS;   // 2 * BB*SS
        int*   flags   = (int*)(Lp + 2 * (size_t)BB * SS);
        // partial O buffers live in the P region (overwritten by pstore later)
        float* Op0 = P;
        float* Op1 = P + nE;

        hipMemsetAsync(flags, 0, 256 * sizeof(int), stream);
        prep_kernel<<<dim3(SS / 64, BB), 256, 0, stream>>>(Q, K, V, mask, Qb, Kb, VT, maskAdd);
        flashA_kernel<<<512, 256, 0, stream>>>(Qb, Kb, VT, maskAdd, Op0, Op1, Lp, O, flags);
        pstore_kernel<<<1024, 256, 0, stream>>>(Qb, Kb, maskAdd, Lp, P);
    } else {
        qk_exp_kernel<<<dim3(SS / 128, SS / 128, BB), 256, 0, stream>>>(Q, K, mask, P);
        norm_kernel<<<(BB * SS) / 4, 256, 0, stream>>>(P);
        pv_fallback_kernel<<<dim3(SS / 64, BB), 256, 0, stream>>>(P, V, O);
    }
}

// Round 9
// 148.936 us; speedup vs baseline: 1.5533x; 1.5533x over previous
//
#include <hip/hip_runtime.h>

#define BB 16
#define SS 2048
#define DD 128
// exp(s/sqrt(128)) = 2^(s * CE),  CE = log2(e)/sqrt(128)
#define CE (0.08838834764831845f * 1.4426950408889634f)

typedef __attribute__((ext_vector_type(4))) float f32x4;
typedef __attribute__((ext_vector_type(8))) short short8;
typedef __attribute__((ext_vector_type(4))) unsigned short us4;
typedef __attribute__((ext_vector_type(8))) unsigned short us8;

__device__ inline unsigned short f2bf(float f) {
    unsigned u = __float_as_uint(f);
    u += 0x7fffu + ((u >> 16) & 1u);   // round-to-nearest-even
    return (unsigned short)(u >> 16);
}

// XOR swizzles (swzA: 256B rows; swzB: 128B rows)
__device__ inline int swzA(int row, int col) {
    int byteoff = (row << 8) + ((col >> 3) << 4);
    byteoff ^= (row & 7) << 4;
    return (byteoff >> 1) + (col & 7);
}
__device__ inline int swzB(int row, int col) {
    int byteoff = (row << 7) + ((col >> 3) << 4);
    byteoff ^= (row & 7) << 4;
    return (byteoff >> 1) + (col & 7);
}

// ---------------------------------------------------------------------------
// prep: Q,K fp32 -> bf16; mask -> additive fp32 (0/-inf); V -> VT bf16.
// grid (S/64, B), 256 thr.
// ---------------------------------------------------------------------------
__global__ __launch_bounds__(256) void prep_kernel(
    const float* __restrict__ Q, const float* __restrict__ K,
    const float* __restrict__ V, const int* __restrict__ mask,
    unsigned short* __restrict__ Qb, unsigned short* __restrict__ Kb,
    unsigned short* __restrict__ VT, float* __restrict__ maskAdd)
{
    __shared__ unsigned short tile[64 * 136];
    int b = blockIdx.y, k0 = blockIdx.x << 6;
    int t = threadIdx.x;
    const size_t base = ((size_t)b * SS + k0) * DD;   // 8192 elements

    for (int i = 0; i < 8; ++i) {
        int f4 = (i << 8) + t;
        f32x4 q = reinterpret_cast<const f32x4*>(Q + base)[f4];
        f32x4 k = reinterpret_cast<const f32x4*>(K + base)[f4];
        us4 qh, kh;
        for (int j = 0; j < 4; ++j) { qh[j] = f2bf(q[j]); kh[j] = f2bf(k[j]); }
        reinterpret_cast<us4*>(Qb + base)[f4] = qh;
        reinterpret_cast<us4*>(Kb + base)[f4] = kh;
    }
    if (t < 64)
        maskAdd[(size_t)b * SS + k0 + t] =
            mask[(size_t)b * SS + k0 + t] ? 0.0f : __int_as_float(0xff800000);

    for (int i = 0; i < 8; ++i) {
        int f4 = (i << 8) + t;
        int k  = f4 >> 5;
        int n  = (f4 & 31) << 2;
        f32x4 v = reinterpret_cast<const f32x4*>(V + base)[f4];
        us4 h;
        for (int j = 0; j < 4; ++j) h[j] = f2bf(v[j]);
        *reinterpret_cast<us4*>(&tile[k * 136 + n]) = h;
    }
    __syncthreads();
    unsigned short* outp = VT + (size_t)b * DD * SS;
    for (int i = 0; i < 4; ++i) {
        int id = (i << 8) + t;
        int n  = id >> 3;
        int c8 = id & 7;
        us8 o;
        for (int j = 0; j < 8; ++j) o[j] = tile[((c8 << 3) + j) * 136 + n];
        *reinterpret_cast<us8*>(&outp[(size_t)n * SS + k0 + (c8 << 3)]) = o;
    }
}

// ---------------------------------------------------------------------------
// flashA: double-buffered, ONE barrier per 64-kv tile. grid 512 (B x 16 qblk
// x 2 kv halves, XCD-grouped), 256 thr, 2 blocks/CU. 32 q/wave.
// Writes partial unnormalized O and partial L. (r7-proven; no fences.)
// ---------------------------------------------------------------------------
__global__ __launch_bounds__(256, 2) void flashA_kernel(
    const unsigned short* __restrict__ Qb, const unsigned short* __restrict__ Kb,
    const unsigned short* __restrict__ VT, const float* __restrict__ maskAdd,
    float* __restrict__ Op0, float* __restrict__ Op1, float* __restrict__ Lp)
{
    __shared__ unsigned short Ks[2][64 * 128];    // 2 x 16 KB
    __shared__ unsigned short VTs[2][128 * 64];   // 2 x 16 KB
    __shared__ unsigned short Ps[4 * 1024];       // per-wave 16q-row x 64col (2 KB)

    const int id = blockIdx.x;
    const int xcd = id & 7, j = id >> 3;
    const int b   = (xcd << 1) | (j >> 5);
    const int rem = j & 31;
    const int half = rem >> 4, qb = rem & 15;
    const int q0 = qb << 7;
    const int kvbase = half << 10;

    const int t = threadIdx.x, lane = t & 63, w = t >> 6;
    const int lr = lane & 15, lg = lane >> 4;

    const unsigned short* Kbb = Kb + (size_t)b * SS * DD;
    const unsigned short* Vbb = VT + (size_t)b * DD * SS;
    const float* Mb = maskAdd + (size_t)b * SS;

    // Q fragments (B-operand): q = q0 + w*32 + m*16 + lr
    const unsigned short* Qp = Qb + ((size_t)b * SS + q0 + w * 32) * DD;
    short8 qf[2][4];
    for (int m = 0; m < 2; ++m)
        for (int kb = 0; kb < 4; ++kb)
            qf[m][kb] = *reinterpret_cast<const short8*>(
                Qp + (size_t)(m * 16 + lr) * DD + kb * 32 + lg * 8);

    f32x4 oacc[2][8] = {};
    float rsum[2] = {0.f, 0.f};
    unsigned short* Pw = &Ps[w * 1024];

    us8 kstg[4], vstg[4];
#define LOADTILE(kv)                                                             \
    for (int i = 0; i < 4; ++i) {                                                \
        int f = i * 256 + t;                                                     \
        kstg[i] = *reinterpret_cast<const us8*>(                                 \
            Kbb + (size_t)((kv) + (f >> 4)) * DD + ((f & 15) << 3));             \
        vstg[i] = *reinterpret_cast<const us8*>(                                 \
            Vbb + (size_t)(f >> 3) * SS + (kv) + ((f & 7) << 3));                \
    }
#define WRITETILE(bf)                                                            \
    for (int i = 0; i < 4; ++i) {                                                \
        int f = i * 256 + t;                                                     \
        *reinterpret_cast<us8*>(&Ks[bf][swzA(f >> 4, (f & 15) << 3)]) = kstg[i]; \
        *reinterpret_cast<us8*>(&VTs[bf][swzB(f >> 3, (f & 7) << 3)]) = vstg[i]; \
    }

    LOADTILE(kvbase);
    WRITETILE(0);

    for (int kt = 0; kt < 16; ++kt) {
        const int cur = kt & 1;
        const int kv0 = kvbase + (kt << 6);
        if (kt + 1 < 16) { LOADTILE(kv0 + 64); }   // T14: latency hides under compute
        __syncthreads();                           // buf[cur] writes visible

        // S^T = K . Q^T  (rows = kv, cols = q) — order identical to pstore
        f32x4 sacc[2][4] = {};
        __builtin_amdgcn_s_setprio(1);
        for (int kb = 0; kb < 4; ++kb) {
            short8 kf[4];
            for (int n = 0; n < 4; ++n)
                kf[n] = *reinterpret_cast<const short8*>(
                    &Ks[cur][swzA(n * 16 + lr, kb * 32 + lg * 8)]);
            for (int n = 0; n < 4; ++n)
                for (int m = 0; m < 2; ++m)
                    sacc[m][n] = __builtin_amdgcn_mfma_f32_16x16x32_bf16(
                        kf[n], qf[m][kb], sacc[m][n], 0, 0, 0);
        }
        __builtin_amdgcn_s_setprio(0);

        // two 32-kv halves: exp -> wave-local P stash -> PV
        for (int h = 0; h < 2; ++h) {
            for (int nl = 0; nl < 2; ++nl) {
                int n = h * 2 + nl;
                f32x4 ma = *reinterpret_cast<const f32x4*>(Mb + kv0 + n * 16 + lg * 4);
                for (int m = 0; m < 2; ++m) {
                    us4 hh;
                    for (int r = 0; r < 4; ++r) {
                        float p = __builtin_amdgcn_exp2f(fmaf(sacc[m][n][r], CE, ma[r]));
                        rsum[m] += p;
                        hh[r] = f2bf(p);
                    }
                    *reinterpret_cast<us4*>(&Pw[swzB(lr, m * 32 + nl * 16 + lg * 4)]) = hh;
                }
            }
            asm volatile("s_waitcnt lgkmcnt(0)" ::: "memory");
            __builtin_amdgcn_sched_barrier(0);

            short8 pf[2];
            for (int m = 0; m < 2; ++m)
                pf[m] = *reinterpret_cast<const short8*>(&Pw[swzB(lr, m * 32 + lg * 8)]);
            __builtin_amdgcn_s_setprio(1);
            for (int nd = 0; nd < 8; ++nd) {
                short8 vf = *reinterpret_cast<const short8*>(
                    &VTs[cur][swzB(nd * 16 + lr, h * 32 + lg * 8)]);
                for (int m = 0; m < 2; ++m)
                    oacc[m][nd] = __builtin_amdgcn_mfma_f32_16x16x32_bf16(
                        pf[m], vf, oacc[m][nd], 0, 0, 0);
            }
            __builtin_amdgcn_s_setprio(0);
        }

        if (kt + 1 < 16) { WRITETILE(cur ^ 1); }   // safe: readers passed barrier above
    }
#undef LOADTILE
#undef WRITETILE

    // reduce L across lg groups; write partial L and unnormalized partial O
    for (int m = 0; m < 2; ++m) {
        rsum[m] += __shfl_xor(rsum[m], 16, 64);
        rsum[m] += __shfl_xor(rsum[m], 32, 64);
    }
    if (lane < 16)
        for (int m = 0; m < 2; ++m)
            Lp[(size_t)half * BB * SS + (size_t)b * SS + q0 + w * 32 + m * 16 + lane] = rsum[m];

    float* Op = half ? Op1 : Op0;
    float* Og = Op + ((size_t)b * SS + q0 + w * 32) * DD;
    for (int m = 0; m < 2; ++m)
        for (int nd = 0; nd < 8; ++nd)
            for (int r = 0; r < 4; ++r)
                Og[(size_t)(m * 16 + lg * 4 + r) * DD + nd * 16 + lr] = oacc[m][nd][r];
}

// ---------------------------------------------------------------------------
// combine (small-ws path only): O = (O0+O1)*inv(L0+L1).
// ---------------------------------------------------------------------------
__global__ __launch_bounds__(256) void combine_kernel(
    const float* __restrict__ Op0, const float* __restrict__ Op1,
    const float* __restrict__ Lp, float* __restrict__ O)
{
    int i = blockIdx.x * 256 + threadIdx.x;   // f32x4 index
    int row = i >> 5;                         // 32 f32x4 per 128-elem row
    float L = Lp[row] + Lp[BB * SS + row];
    float il = L > 0.f ? 1.f / L : 0.f;
    f32x4 a = reinterpret_cast<const f32x4*>(Op0)[i];
    f32x4 c = reinterpret_cast<const f32x4*>(Op1)[i];
    f32x4 o;
    for (int r = 0; r < 4; ++r) o[r] = (a[r] + c[r]) * il;
    reinterpret_cast<f32x4*>(O)[i] = o;
}

// ---------------------------------------------------------------------------
// pstore: double-buffered K staging, ONE barrier per tile. Computes its own
// log2(1/L) from Lp; recomputes S^T bit-identically; writes
// P = 2^(s*CE + maskAdd + lil). grid 1024 (kv-split 4), 256 thr, 4 blocks/CU.
// DO_COMBINE: kvq==0 blocks also write final O from ws-resident partials
// (ordering vs flashA is the kernel boundary — no fences).
// ---------------------------------------------------------------------------
template<bool DO_COMBINE>
__global__ __launch_bounds__(256, 4) void pstore_kernel(
    const unsigned short* __restrict__ Qb, const unsigned short* __restrict__ Kb,
    const float* __restrict__ maskAdd, const float* __restrict__ Lp,
    float* __restrict__ P,
    const float* __restrict__ Op0, const float* __restrict__ Op1,
    float* __restrict__ O)
{
    __shared__ unsigned short Ks[2][64 * 128];

    const int id = blockIdx.x;
    const int xcd = id & 7, j = id >> 3;          // grid 1024
    const int b   = (xcd << 1) | (j >> 6);
    const int rem = j & 63;
    const int kvq = rem >> 4, qb = rem & 15;
    const int q0 = qb << 7, kvbase = kvq << 9;

    const int t = threadIdx.x, lane = t & 63, w = t >> 6;
    const int lr = lane & 15, lg = lane >> 4;

    const unsigned short* Kbb = Kb + (size_t)b * SS * DD;
    const float* Mb = maskAdd + (size_t)b * SS;

    const unsigned short* Qp = Qb + ((size_t)b * SS + q0 + w * 32) * DD;
    short8 qf[2][4];
    for (int m = 0; m < 2; ++m)
        for (int kb = 0; kb < 4; ++kb)
            qf[m][kb] = *reinterpret_cast<const short8*>(
                Qp + (size_t)(m * 16 + lr) * DD + kb * 32 + lg * 8);

    float lil[2];
    for (int m = 0; m < 2; ++m) {
        size_t rowi = (size_t)b * SS + q0 + w * 32 + m * 16 + lr;
        float L = Lp[rowi] + Lp[(size_t)BB * SS + rowi];
        lil[m] = L > 0.f ? -__builtin_amdgcn_logf(L) : __int_as_float(0xff800000);
    }

    us8 kstg[4];
#define LOADK(kv)                                                                \
    for (int i = 0; i < 4; ++i) {                                                \
        int f = i * 256 + t;                                                     \
        kstg[i] = *reinterpret_cast<const us8*>(                                 \
            Kbb + (size_t)((kv) + (f >> 4)) * DD + ((f & 15) << 3));             \
    }
#define WRITEK(bf)                                                               \
    for (int i = 0; i < 4; ++i) {                                                \
        int f = i * 256 + t;                                                     \
        *reinterpret_cast<us8*>(&Ks[bf][swzA(f >> 4, (f & 15) << 3)]) = kstg[i]; \
    }

    LOADK(kvbase);
    WRITEK(0);

    for (int kt = 0; kt < 8; ++kt) {
        const int cur = kt & 1;
        const int kv0 = kvbase + (kt << 6);
        if (kt + 1 < 8) { LOADK(kv0 + 64); }
        __syncthreads();

        // identical structure/order to flashA -> bit-identical sacc
        f32x4 sacc[2][4] = {};
        for (int kb = 0; kb < 4; ++kb) {
            short8 kf[4];
            for (int n = 0; n < 4; ++n)
                kf[n] = *reinterpret_cast<const short8*>(
                    &Ks[cur][swzA(n * 16 + lr, kb * 32 + lg * 8)]);
            for (int n = 0; n < 4; ++n)
                for (int m = 0; m < 2; ++m)
                    sacc[m][n] = __builtin_amdgcn_mfma_f32_16x16x32_bf16(
                        kf[n], qf[m][kb], sacc[m][n], 0, 0, 0);
        }

        for (int m = 0; m < 2; ++m) {
            float* Pp = P + ((size_t)b * SS + q0 + w * 32 + m * 16 + lr) * SS + kv0;
            for (int n = 0; n < 4; ++n) {
                f32x4 ma = *reinterpret_cast<const f32x4*>(Mb + kv0 + n * 16 + lg * 4);
                f32x4 out;
                for (int r = 0; r < 4; ++r)
                    out[r] = __builtin_amdgcn_exp2f(
                        fmaf(sacc[m][n][r], CE, ma[r]) + lil[m]);
                *reinterpret_cast<f32x4*>(Pp + n * 16 + lg * 4) = out;
            }
        }

        if (kt + 1 < 8) { WRITEK(cur ^ 1); }
    }
#undef LOADK
#undef WRITEK

    // combine (ws-resident partials): one designated block per (b,qb) slab
    if (DO_COMBINE && kvq == 0) {
        const f32x4* PA = reinterpret_cast<const f32x4*>(Op0 + ((size_t)b * SS + q0) * DD);
        const f32x4* PB = reinterpret_cast<const f32x4*>(Op1 + ((size_t)b * SS + q0) * DD);
        f32x4* Of = reinterpret_cast<f32x4*>(O + ((size_t)b * SS + q0) * DD);
        const float* L0 = Lp + (size_t)b * SS + q0;
        const float* L1 = Lp + (size_t)BB * SS + (size_t)b * SS + q0;
        for (int i = 0; i < 16; ++i) {
            int idx = i * 256 + t;    // 4096 f32x4 in the 128x128 slab
            int row = idx >> 5;
            float L = L0[row] + L1[row];
            float il = L > 0.f ? 1.f / L : 0.f;
            f32x4 a = PA[idx], c = PB[idx];
            f32x4 o;
            for (int r = 0; r < 4; ++r) o[r] = (a[r] + c[r]) * il;
            Of[idx] = o;
        }
    }
}

// ---------------------------------------------------------------------------
// Fallback pipeline (no workspace requirements)
// ---------------------------------------------------------------------------
__global__ __launch_bounds__(256) void qk_exp_kernel(
    const float* __restrict__ Q, const float* __restrict__ Kin,
    const int* __restrict__ mask, float* __restrict__ P)
{
    __shared__ unsigned short Qs[128 * 128];
    __shared__ unsigned short Ks[128 * 128];
    const int b  = blockIdx.z;
    const int m0 = blockIdx.y << 7;
    const int n0 = blockIdx.x << 7;
    const int t  = threadIdx.x;
    const float* Qp = Q   + ((size_t)b * SS + m0) * DD;
    const float* Kp = Kin + ((size_t)b * SS + n0) * DD;
    for (int i = 0; i < 16; ++i) {
        int f4  = (i << 8) + t;
        int row = f4 >> 5;
        int col = (f4 & 31) << 2;
        f32x4 q = reinterpret_cast<const f32x4*>(Qp)[f4];
        f32x4 k = reinterpret_cast<const f32x4*>(Kp)[f4];
        us4 qh, kh;
        for (int jj = 0; jj < 4; ++jj) { qh[jj] = f2bf(q[jj]); kh[jj] = f2bf(k[jj]); }
        *reinterpret_cast<us4*>(&Qs[swzA(row, col)]) = qh;
        *reinterpret_cast<us4*>(&Ks[swzA(row, col)]) = kh;
    }
    __syncthreads();
    const int lane = t & 63, wid = t >> 6;
    const int wr = wid >> 1, wc = wid & 1;
    const int lr = lane & 15, lg = lane >> 4;
    f32x4 acc[4][4] = {};
    for (int kb = 0; kb < 4; ++kb) {
        short8 a[4], bq[4];
        int kcol = (kb << 5) + (lg << 3);
        for (int m = 0; m < 4; ++m)
            a[m] = *reinterpret_cast<const short8*>(&Qs[swzA((wr << 6) + (m << 4) + lr, kcol)]);
        for (int n = 0; n < 4; ++n)
            bq[n] = *reinterpret_cast<const short8*>(&Ks[swzA((wc << 6) + (n << 4) + lr, kcol)]);
        for (int m = 0; m < 4; ++m)
            for (int n = 0; n < 4; ++n)
                acc[m][n] = __builtin_amdgcn_mfma_f32_16x16x32_bf16(a[m], bq[n], acc[m][n], 0, 0, 0);
    }
    const int* am = mask + (size_t)b * SS;
    for (int n = 0; n < 4; ++n) {
        int col = n0 + (wc << 6) + (n << 4) + lr;
        bool allow = am[col] != 0;
        for (int m = 0; m < 4; ++m) {
            int rowb = m0 + (wr << 6) + (m << 4) + (lg << 2);
            float* Pp = P + ((size_t)b * SS + rowb) * SS + col;
            for (int r = 0; r < 4; ++r) {
                float p = allow ? __expf(acc[m][n][r] * 0.08838834764831845f) : 0.0f;
                Pp[(size_t)r * SS] = p;
            }
        }
    }
}

__global__ __launch_bounds__(256) void norm_kernel(float* __restrict__ P)
{
    int row  = (blockIdx.x << 2) + (threadIdx.x >> 6);
    int lane = threadIdx.x & 63;
    float* Pr = P + (size_t)row * SS;
    f32x4 v[8];
    float sum = 0.f;
    for (int i = 0; i < 8; ++i) {
        v[i] = reinterpret_cast<f32x4*>(Pr)[(i << 6) + lane];
        sum += v[i][0] + v[i][1] + v[i][2] + v[i][3];
    }
    for (int off = 1; off < 64; off <<= 1) sum += __shfl_xor(sum, off, 64);
    float inv = sum > 0.f ? 1.f / sum : 0.f;
    for (int i = 0; i < 8; ++i) {
        f32x4 wv = v[i];
        for (int jj = 0; jj < 4; ++jj) wv[jj] *= inv;
        reinterpret_cast<f32x4*>(Pr)[(i << 6) + lane] = wv;
    }
}

__global__ __launch_bounds__(256) void pv_fallback_kernel(
    const float* __restrict__ P, const float* __restrict__ V, float* __restrict__ O)
{
    __shared__ unsigned short Ws[64 * 64];
    const int b  = blockIdx.y;
    const int m0 = blockIdx.x << 6;
    const int t  = threadIdx.x, lane = t & 63, wid = t >> 6;
    const int wr = wid >> 1, wc = wid & 1;
    const int lr = lane & 15, lg = lane >> 4;
    const float* Pg = P + ((size_t)b * SS + m0) * SS;
    f32x4 acc[2][4] = {};
    for (int k0 = 0; k0 < SS; k0 += 64) {
        __syncthreads();
        for (int i = 0; i < 4; ++i) {
            int f4  = (i << 8) + t;
            int row = f4 >> 4;
            int col = (f4 & 15) << 2;
            f32x4 wv = *reinterpret_cast<const f32x4*>(Pg + (size_t)row * SS + k0 + col);
            us4 h;
            for (int jj = 0; jj < 4; ++jj) h[jj] = f2bf(wv[jj]);
            *reinterpret_cast<us4*>(&Ws[swzB(row, col)]) = h;
        }
        __syncthreads();
        for (int kk = 0; kk < 64; kk += 32) {
            short8 a[2], bv[4];
            int kcol = kk + (lg << 3);
            for (int m = 0; m < 2; ++m)
                a[m] = *reinterpret_cast<const short8*>(&Ws[swzB((wr << 5) + (m << 4) + lr, kcol)]);
            for (int n = 0; n < 4; ++n) {
                int col = (wc << 6) + (n << 4) + lr;
                const float* vp = V + ((size_t)b * SS + k0 + kcol) * DD + col;
                short8 x;
                for (int jj = 0; jj < 8; ++jj) x[jj] = (short)f2bf(vp[(size_t)jj * DD]);
                bv[n] = x;
            }
            for (int m = 0; m < 2; ++m)
                for (int n = 0; n < 4; ++n)
                    acc[m][n] = __builtin_amdgcn_mfma_f32_16x16x32_bf16(a[m], bv[n], acc[m][n], 0, 0, 0);
        }
    }
    float* Og = O + ((size_t)b * SS + m0) * DD;
    for (int m = 0; m < 2; ++m)
        for (int n = 0; n < 4; ++n)
            for (int r = 0; r < 4; ++r)
                Og[(size_t)((wr << 5) + (m << 4) + (lg << 2) + r) * DD
                   + (wc << 6) + (n << 4) + lr] = acc[m][n][r];
}

// ---------------------------------------------------------------------------
extern "C" void kernel_launch(void* const* d_in, const int* in_sizes, int n_in,
                              void* d_out, int out_size, void* d_ws, size_t ws_size,
                              hipStream_t stream)
{
    const float* Q  = (const float*)d_in[0];
    const float* K  = (const float*)d_in[1];
    const float* V  = (const float*)d_in[2];
    const int* mask = (const int*)d_in[3];
    float* O = (float*)d_out;
    float* P = O + (size_t)BB * SS * DD;

    const size_t nE = (size_t)BB * SS * DD;   // 4194304 elements per tensor
    const size_t need_base = 3 * nE * sizeof(unsigned short)
                           + 3 * (size_t)BB * SS * sizeof(float) + 256;
    const size_t need_big  = need_base + 2 * nE * sizeof(float);

    if (ws_size >= need_base) {
        unsigned short* Qb = (unsigned short*)d_ws;
        unsigned short* Kb = Qb + nE;
        unsigned short* VT = Kb + nE;
        float* maskAdd = (float*)(VT + nE);
        float* Lp      = maskAdd + (size_t)BB * SS;   // 2 * BB*SS

        prep_kernel<<<dim3(SS / 64, BB), 256, 0, stream>>>(Q, K, V, mask, Qb, Kb, VT, maskAdd);

        if (ws_size >= need_big) {
            // partials in ws -> combine folded into pstore (no extra kernel)
            float* Op0 = Lp + 2 * (size_t)BB * SS;
            float* Op1 = Op0 + nE;
            flashA_kernel<<<512, 256, 0, stream>>>(Qb, Kb, VT, maskAdd, Op0, Op1, Lp);
            pstore_kernel<true><<<1024, 256, 0, stream>>>(Qb, Kb, maskAdd, Lp, P, Op0, Op1, O);
        } else {
            // partials in P region -> separate combine between flashA and pstore
            float* Op0 = P;
            float* Op1 = P + nE;
            flashA_kernel<<<512, 256, 0, stream>>>(Qb, Kb, VT, maskAdd, Op0, Op1, Lp);
            combine_kernel<<<4096, 256, 0, stream>>>(Op0, Op1, Lp, O);
            pstore_kernel<false><<<1024, 256, 0, stream>>>(Qb, Kb, maskAdd, Lp, P,
                                                           nullptr, nullptr, nullptr);
        }
    } else {
        qk_exp_kernel<<<dim3(SS / 128, SS / 128, BB), 256, 0, stream>>>(Q, K, mask, P);
        norm_kernel<<<(BB * SS) / 4, 256, 0, stream>>>(P);
        pv_fallback_kernel<<<dim3(SS / 64, BB), 256, 0, stream>>>(P, V, O);
    }
}

// Round 10
// 144.353 us; speedup vs baseline: 1.6027x; 1.0317x over previous
//
#include <hip/hip_runtime.h>

#define BB 16
#define SS 2048
#define DD 128
// exp(s/sqrt(128)) = 2^(s * CE),  CE = log2(e)/sqrt(128)
#define CE (0.08838834764831845f * 1.4426950408889634f)

typedef __attribute__((ext_vector_type(4))) float f32x4;
typedef __attribute__((ext_vector_type(8))) short short8;
typedef __attribute__((ext_vector_type(4))) unsigned short us4;
typedef __attribute__((ext_vector_type(8))) unsigned short us8;

__device__ inline unsigned short f2bf(float f) {
    unsigned u = __float_as_uint(f);
    u += 0x7fffu + ((u >> 16) & 1u);   // round-to-nearest-even
    return (unsigned short)(u >> 16);
}

// XOR swizzles (swzA: 256B rows; swzB: 128B rows)
__device__ inline int swzA(int row, int col) {
    int byteoff = (row << 8) + ((col >> 3) << 4);
    byteoff ^= (row & 7) << 4;
    return (byteoff >> 1) + (col & 7);
}
__device__ inline int swzB(int row, int col) {
    int byteoff = (row << 7) + ((col >> 3) << 4);
    byteoff ^= (row & 7) << 4;
    return (byteoff >> 1) + (col & 7);
}

// ---------------------------------------------------------------------------
// prep: Q,K fp32 -> bf16; mask -> additive fp32 (0/-inf); V -> VT bf16.
// grid (S/64, B), 256 thr.
// ---------------------------------------------------------------------------
__global__ __launch_bounds__(256) void prep_kernel(
    const float* __restrict__ Q, const float* __restrict__ K,
    const float* __restrict__ V, const int* __restrict__ mask,
    unsigned short* __restrict__ Qb, unsigned short* __restrict__ Kb,
    unsigned short* __restrict__ VT, float* __restrict__ maskAdd)
{
    __shared__ unsigned short tile[64 * 136];
    int b = blockIdx.y, k0 = blockIdx.x << 6;
    int t = threadIdx.x;
    const size_t base = ((size_t)b * SS + k0) * DD;   // 8192 elements

    for (int i = 0; i < 8; ++i) {
        int f4 = (i << 8) + t;
        f32x4 q = reinterpret_cast<const f32x4*>(Q + base)[f4];
        f32x4 k = reinterpret_cast<const f32x4*>(K + base)[f4];
        us4 qh, kh;
        for (int j = 0; j < 4; ++j) { qh[j] = f2bf(q[j]); kh[j] = f2bf(k[j]); }
        reinterpret_cast<us4*>(Qb + base)[f4] = qh;
        reinterpret_cast<us4*>(Kb + base)[f4] = kh;
    }
    if (t < 64)
        maskAdd[(size_t)b * SS + k0 + t] =
            mask[(size_t)b * SS + k0 + t] ? 0.0f : __int_as_float(0xff800000);

    for (int i = 0; i < 8; ++i) {
        int f4 = (i << 8) + t;
        int k  = f4 >> 5;
        int n  = (f4 & 31) << 2;
        f32x4 v = reinterpret_cast<const f32x4*>(V + base)[f4];
        us4 h;
        for (int j = 0; j < 4; ++j) h[j] = f2bf(v[j]);
        *reinterpret_cast<us4*>(&tile[k * 136 + n]) = h;
    }
    __syncthreads();
    unsigned short* outp = VT + (size_t)b * DD * SS;
    for (int i = 0; i < 4; ++i) {
        int id = (i << 8) + t;
        int n  = id >> 3;
        int c8 = id & 7;
        us8 o;
        for (int j = 0; j < 8; ++j) o[j] = tile[((c8 << 3) + j) * 136 + n];
        *reinterpret_cast<us8*>(&outp[(size_t)n * SS + k0 + (c8 << 3)]) = o;
    }
}

// ---------------------------------------------------------------------------
// flashA: double-buffered, ONE barrier per 64-kv tile. grid 512 (B x 16 qblk
// x 2 kv halves, XCD-grouped), 256 thr, 2 blocks/CU. 32 q/wave.
// Writes partial unnormalized O and partial L. (r7-proven; no fences.)
// ---------------------------------------------------------------------------
__global__ __launch_bounds__(256, 2) void flashA_kernel(
    const unsigned short* __restrict__ Qb, const unsigned short* __restrict__ Kb,
    const unsigned short* __restrict__ VT, const float* __restrict__ maskAdd,
    float* __restrict__ Op0, float* __restrict__ Op1, float* __restrict__ Lp)
{
    __shared__ unsigned short Ks[2][64 * 128];    // 2 x 16 KB
    __shared__ unsigned short VTs[2][128 * 64];   // 2 x 16 KB
    __shared__ unsigned short Ps[4 * 1024];       // per-wave 16q-row x 64col (2 KB)

    const int id = blockIdx.x;
    const int xcd = id & 7, j = id >> 3;
    const int b   = (xcd << 1) | (j >> 5);
    const int rem = j & 31;
    const int half = rem >> 4, qb = rem & 15;
    const int q0 = qb << 7;
    const int kvbase = half << 10;

    const int t = threadIdx.x, lane = t & 63, w = t >> 6;
    const int lr = lane & 15, lg = lane >> 4;

    const unsigned short* Kbb = Kb + (size_t)b * SS * DD;
    const unsigned short* Vbb = VT + (size_t)b * DD * SS;
    const float* Mb = maskAdd + (size_t)b * SS;

    // Q fragments (B-operand): q = q0 + w*32 + m*16 + lr
    const unsigned short* Qp = Qb + ((size_t)b * SS + q0 + w * 32) * DD;
    short8 qf[2][4];
    for (int m = 0; m < 2; ++m)
        for (int kb = 0; kb < 4; ++kb)
            qf[m][kb] = *reinterpret_cast<const short8*>(
                Qp + (size_t)(m * 16 + lr) * DD + kb * 32 + lg * 8);

    f32x4 oacc[2][8] = {};
    float rsum[2] = {0.f, 0.f};
    unsigned short* Pw = &Ps[w * 1024];

    us8 kstg[4], vstg[4];
#define LOADTILE(kv)                                                             \
    for (int i = 0; i < 4; ++i) {                                                \
        int f = i * 256 + t;                                                     \
        kstg[i] = *reinterpret_cast<const us8*>(                                 \
            Kbb + (size_t)((kv) + (f >> 4)) * DD + ((f & 15) << 3));             \
        vstg[i] = *reinterpret_cast<const us8*>(                                 \
            Vbb + (size_t)(f >> 3) * SS + (kv) + ((f & 7) << 3));                \
    }
#define WRITETILE(bf)                                                            \
    for (int i = 0; i < 4; ++i) {                                                \
        int f = i * 256 + t;                                                     \
        *reinterpret_cast<us8*>(&Ks[bf][swzA(f >> 4, (f & 15) << 3)]) = kstg[i]; \
        *reinterpret_cast<us8*>(&VTs[bf][swzB(f >> 3, (f & 7) << 3)]) = vstg[i]; \
    }

    LOADTILE(kvbase);
    WRITETILE(0);

    for (int kt = 0; kt < 16; ++kt) {
        const int cur = kt & 1;
        const int kv0 = kvbase + (kt << 6);
        if (kt + 1 < 16) { LOADTILE(kv0 + 64); }   // T14: latency hides under compute
        __syncthreads();                           // buf[cur] writes visible

        // S^T = K . Q^T  (rows = kv, cols = q) — order identical to pstore
        f32x4 sacc[2][4] = {};
        __builtin_amdgcn_s_setprio(1);
        for (int kb = 0; kb < 4; ++kb) {
            short8 kf[4];
            for (int n = 0; n < 4; ++n)
                kf[n] = *reinterpret_cast<const short8*>(
                    &Ks[cur][swzA(n * 16 + lr, kb * 32 + lg * 8)]);
            for (int n = 0; n < 4; ++n)
                for (int m = 0; m < 2; ++m)
                    sacc[m][n] = __builtin_amdgcn_mfma_f32_16x16x32_bf16(
                        kf[n], qf[m][kb], sacc[m][n], 0, 0, 0);
        }
        __builtin_amdgcn_s_setprio(0);

        // two 32-kv halves: exp -> wave-local P stash -> PV
        for (int h = 0; h < 2; ++h) {
            for (int nl = 0; nl < 2; ++nl) {
                int n = h * 2 + nl;
                f32x4 ma = *reinterpret_cast<const f32x4*>(Mb + kv0 + n * 16 + lg * 4);
                for (int m = 0; m < 2; ++m) {
                    us4 hh;
                    for (int r = 0; r < 4; ++r) {
                        float p = __builtin_amdgcn_exp2f(fmaf(sacc[m][n][r], CE, ma[r]));
                        rsum[m] += p;
                        hh[r] = f2bf(p);
                    }
                    *reinterpret_cast<us4*>(&Pw[swzB(lr, m * 32 + nl * 16 + lg * 4)]) = hh;
                }
            }
            asm volatile("s_waitcnt lgkmcnt(0)" ::: "memory");
            __builtin_amdgcn_sched_barrier(0);

            short8 pf[2];
            for (int m = 0; m < 2; ++m)
                pf[m] = *reinterpret_cast<const short8*>(&Pw[swzB(lr, m * 32 + lg * 8)]);
            __builtin_amdgcn_s_setprio(1);
            for (int nd = 0; nd < 8; ++nd) {
                short8 vf = *reinterpret_cast<const short8*>(
                    &VTs[cur][swzB(nd * 16 + lr, h * 32 + lg * 8)]);
                for (int m = 0; m < 2; ++m)
                    oacc[m][nd] = __builtin_amdgcn_mfma_f32_16x16x32_bf16(
                        pf[m], vf, oacc[m][nd], 0, 0, 0);
            }
            __builtin_amdgcn_s_setprio(0);
        }

        if (kt + 1 < 16) { WRITETILE(cur ^ 1); }   // safe: readers passed barrier above
    }
#undef LOADTILE
#undef WRITETILE

    // reduce L across lg groups; write partial L and unnormalized partial O
    for (int m = 0; m < 2; ++m) {
        rsum[m] += __shfl_xor(rsum[m], 16, 64);
        rsum[m] += __shfl_xor(rsum[m], 32, 64);
    }
    if (lane < 16)
        for (int m = 0; m < 2; ++m)
            Lp[(size_t)half * BB * SS + (size_t)b * SS + q0 + w * 32 + m * 16 + lane] = rsum[m];

    float* Op = half ? Op1 : Op0;
    float* Og = Op + ((size_t)b * SS + q0 + w * 32) * DD;
    for (int m = 0; m < 2; ++m)
        for (int nd = 0; nd < 8; ++nd)
            for (int r = 0; r < 4; ++r)
                Og[(size_t)(m * 16 + lg * 4 + r) * DD + nd * 16 + lr] = oacc[m][nd][r];
}

// ---------------------------------------------------------------------------
// combine (small-ws path only): O = (O0+O1)*inv(L0+L1).
// ---------------------------------------------------------------------------
__global__ __launch_bounds__(256) void combine_kernel(
    const float* __restrict__ Op0, const float* __restrict__ Op1,
    const float* __restrict__ Lp, float* __restrict__ O)
{
    int i = blockIdx.x * 256 + threadIdx.x;   // f32x4 index
    int row = i >> 5;                         // 32 f32x4 per 128-elem row
    float L = Lp[row] + Lp[BB * SS + row];
    float il = L > 0.f ? 1.f / L : 0.f;
    f32x4 a = reinterpret_cast<const f32x4*>(Op0)[i];
    f32x4 c = reinterpret_cast<const f32x4*>(Op1)[i];
    f32x4 o;
    for (int r = 0; r < 4; ++r) o[r] = (a[r] + c[r]) * il;
    reinterpret_cast<f32x4*>(O)[i] = o;
}

// ---------------------------------------------------------------------------
// pstore: double-buffered K staging, ONE barrier per tile. Computes its own
// log2(1/L) from Lp; recomputes S^T bit-identically; writes
// P = 2^(s*CE + maskAdd + lil). grid 1024 (kv-split 4), 256 thr, 4 blocks/CU.
// DO_COMBINE: every block also combines a BALANCED 32-row O slice
// (rows q0 + kvq*32 .. +32) from ws-resident partials — kernel-boundary
// ordering vs flashA, no fences (r8 lesson), no tail imbalance (r9 lesson).
// ---------------------------------------------------------------------------
template<bool DO_COMBINE>
__global__ __launch_bounds__(256, 4) void pstore_kernel(
    const unsigned short* __restrict__ Qb, const unsigned short* __restrict__ Kb,
    const float* __restrict__ maskAdd, const float* __restrict__ Lp,
    float* __restrict__ P,
    const float* __restrict__ Op0, const float* __restrict__ Op1,
    float* __restrict__ O)
{
    __shared__ unsigned short Ks[2][64 * 128];

    const int id = blockIdx.x;
    const int xcd = id & 7, j = id >> 3;          // grid 1024
    const int b   = (xcd << 1) | (j >> 6);
    const int rem = j & 63;
    const int kvq = rem >> 4, qb = rem & 15;
    const int q0 = qb << 7, kvbase = kvq << 9;

    const int t = threadIdx.x, lane = t & 63, w = t >> 6;
    const int lr = lane & 15, lg = lane >> 4;

    const unsigned short* Kbb = Kb + (size_t)b * SS * DD;
    const float* Mb = maskAdd + (size_t)b * SS;

    const unsigned short* Qp = Qb + ((size_t)b * SS + q0 + w * 32) * DD;
    short8 qf[2][4];
    for (int m = 0; m < 2; ++m)
        for (int kb = 0; kb < 4; ++kb)
            qf[m][kb] = *reinterpret_cast<const short8*>(
                Qp + (size_t)(m * 16 + lr) * DD + kb * 32 + lg * 8);

    float lil[2];
    for (int m = 0; m < 2; ++m) {
        size_t rowi = (size_t)b * SS + q0 + w * 32 + m * 16 + lr;
        float L = Lp[rowi] + Lp[(size_t)BB * SS + rowi];
        lil[m] = L > 0.f ? -__builtin_amdgcn_logf(L) : __int_as_float(0xff800000);
    }

    us8 kstg[4];
#define LOADK(kv)                                                                \
    for (int i = 0; i < 4; ++i) {                                                \
        int f = i * 256 + t;                                                     \
        kstg[i] = *reinterpret_cast<const us8*>(                                 \
            Kbb + (size_t)((kv) + (f >> 4)) * DD + ((f & 15) << 3));             \
    }
#define WRITEK(bf)                                                               \
    for (int i = 0; i < 4; ++i) {                                                \
        int f = i * 256 + t;                                                     \
        *reinterpret_cast<us8*>(&Ks[bf][swzA(f >> 4, (f & 15) << 3)]) = kstg[i]; \
    }

    LOADK(kvbase);
    WRITEK(0);

    for (int kt = 0; kt < 8; ++kt) {
        const int cur = kt & 1;
        const int kv0 = kvbase + (kt << 6);
        if (kt + 1 < 8) { LOADK(kv0 + 64); }
        __syncthreads();

        // identical structure/order to flashA -> bit-identical sacc
        f32x4 sacc[2][4] = {};
        for (int kb = 0; kb < 4; ++kb) {
            short8 kf[4];
            for (int n = 0; n < 4; ++n)
                kf[n] = *reinterpret_cast<const short8*>(
                    &Ks[cur][swzA(n * 16 + lr, kb * 32 + lg * 8)]);
            for (int n = 0; n < 4; ++n)
                for (int m = 0; m < 2; ++m)
                    sacc[m][n] = __builtin_amdgcn_mfma_f32_16x16x32_bf16(
                        kf[n], qf[m][kb], sacc[m][n], 0, 0, 0);
        }

        for (int m = 0; m < 2; ++m) {
            float* Pp = P + ((size_t)b * SS + q0 + w * 32 + m * 16 + lr) * SS + kv0;
            for (int n = 0; n < 4; ++n) {
                f32x4 ma = *reinterpret_cast<const f32x4*>(Mb + kv0 + n * 16 + lg * 4);
                f32x4 out;
                for (int r = 0; r < 4; ++r)
                    out[r] = __builtin_amdgcn_exp2f(
                        fmaf(sacc[m][n][r], CE, ma[r]) + lil[m]);
                *reinterpret_cast<f32x4*>(Pp + n * 16 + lg * 4) = out;
            }
        }

        if (kt + 1 < 8) { WRITEK(cur ^ 1); }
    }
#undef LOADK
#undef WRITEK

    // balanced combine: this block's 32-row slice (rows q0 + kvq*32 .. +32)
    if (DO_COMBINE) {
        const size_t rbase = (size_t)b * SS + q0 + kvq * 32;
        const f32x4* PA = reinterpret_cast<const f32x4*>(Op0 + rbase * DD);
        const f32x4* PB = reinterpret_cast<const f32x4*>(Op1 + rbase * DD);
        f32x4* Of = reinterpret_cast<f32x4*>(O + rbase * DD);
        const float* L0 = Lp + rbase;
        const float* L1 = Lp + (size_t)BB * SS + rbase;
        for (int i = 0; i < 4; ++i) {
            int idx = i * 256 + t;    // 1024 f32x4 in the 32x128 slice
            int row = idx >> 5;       // 32 f32x4 per row
            float L = L0[row] + L1[row];
            float il = L > 0.f ? 1.f / L : 0.f;
            f32x4 a = PA[idx], c = PB[idx];
            f32x4 o;
            for (int r = 0; r < 4; ++r) o[r] = (a[r] + c[r]) * il;
            Of[idx] = o;
        }
    }
}

// ---------------------------------------------------------------------------
// Fallback pipeline (no workspace requirements)
// ---------------------------------------------------------------------------
__global__ __launch_bounds__(256) void qk_exp_kernel(
    const float* __restrict__ Q, const float* __restrict__ Kin,
    const int* __restrict__ mask, float* __restrict__ P)
{
    __shared__ unsigned short Qs[128 * 128];
    __shared__ unsigned short Ks[128 * 128];
    const int b  = blockIdx.z;
    const int m0 = blockIdx.y << 7;
    const int n0 = blockIdx.x << 7;
    const int t  = threadIdx.x;
    const float* Qp = Q   + ((size_t)b * SS + m0) * DD;
    const float* Kp = Kin + ((size_t)b * SS + n0) * DD;
    for (int i = 0; i < 16; ++i) {
        int f4  = (i << 8) + t;
        int row = f4 >> 5;
        int col = (f4 & 31) << 2;
        f32x4 q = reinterpret_cast<const f32x4*>(Qp)[f4];
        f32x4 k = reinterpret_cast<const f32x4*>(Kp)[f4];
        us4 qh, kh;
        for (int jj = 0; jj < 4; ++jj) { qh[jj] = f2bf(q[jj]); kh[jj] = f2bf(k[jj]); }
        *reinterpret_cast<us4*>(&Qs[swzA(row, col)]) = qh;
        *reinterpret_cast<us4*>(&Ks[swzA(row, col)]) = kh;
    }
    __syncthreads();
    const int lane = t & 63, wid = t >> 6;
    const int wr = wid >> 1, wc = wid & 1;
    const int lr = lane & 15, lg = lane >> 4;
    f32x4 acc[4][4] = {};
    for (int kb = 0; kb < 4; ++kb) {
        short8 a[4], bq[4];
        int kcol = (kb << 5) + (lg << 3);
        for (int m = 0; m < 4; ++m)
            a[m] = *reinterpret_cast<const short8*>(&Qs[swzA((wr << 6) + (m << 4) + lr, kcol)]);
        for (int n = 0; n < 4; ++n)
            bq[n] = *reinterpret_cast<const short8*>(&Ks[swzA((wc << 6) + (n << 4) + lr, kcol)]);
        for (int m = 0; m < 4; ++m)
            for (int n = 0; n < 4; ++n)
                acc[m][n] = __builtin_amdgcn_mfma_f32_16x16x32_bf16(a[m], bq[n], acc[m][n], 0, 0, 0);
    }
    const int* am = mask + (size_t)b * SS;
    for (int n = 0; n < 4; ++n) {
        int col = n0 + (wc << 6) + (n << 4) + lr;
        bool allow = am[col] != 0;
        for (int m = 0; m < 4; ++m) {
            int rowb = m0 + (wr << 6) + (m << 4) + (lg << 2);
            float* Pp = P + ((size_t)b * SS + rowb) * SS + col;
            for (int r = 0; r < 4; ++r) {
                float p = allow ? __expf(acc[m][n][r] * 0.08838834764831845f) : 0.0f;
                Pp[(size_t)r * SS] = p;
            }
        }
    }
}

__global__ __launch_bounds__(256) void norm_kernel(float* __restrict__ P)
{
    int row  = (blockIdx.x << 2) + (threadIdx.x >> 6);
    int lane = threadIdx.x & 63;
    float* Pr = P + (size_t)row * SS;
    f32x4 v[8];
    float sum = 0.f;
    for (int i = 0; i < 8; ++i) {
        v[i] = reinterpret_cast<f32x4*>(Pr)[(i << 6) + lane];
        sum += v[i][0] + v[i][1] + v[i][2] + v[i][3];
    }
    for (int off = 1; off < 64; off <<= 1) sum += __shfl_xor(sum, off, 64);
    float inv = sum > 0.f ? 1.f / sum : 0.f;
    for (int i = 0; i < 8; ++i) {
        f32x4 wv = v[i];
        for (int jj = 0; jj < 4; ++jj) wv[jj] *= inv;
        reinterpret_cast<f32x4*>(Pr)[(i << 6) + lane] = wv;
    }
}

__global__ __launch_bounds__(256) void pv_fallback_kernel(
    const float* __restrict__ P, const float* __restrict__ V, float* __restrict__ O)
{
    __shared__ unsigned short Ws[64 * 64];
    const int b  = blockIdx.y;
    const int m0 = blockIdx.x << 6;
    const int t  = threadIdx.x, lane = t & 63, wid = t >> 6;
    const int wr = wid >> 1, wc = wid & 1;
    const int lr = lane & 15, lg = lane >> 4;
    const float* Pg = P + ((size_t)b * SS + m0) * SS;
    f32x4 acc[2][4] = {};
    for (int k0 = 0; k0 < SS; k0 += 64) {
        __syncthreads();
        for (int i = 0; i < 4; ++i) {
            int f4  = (i << 8) + t;
            int row = f4 >> 4;
            int col = (f4 & 15) << 2;
            f32x4 wv = *reinterpret_cast<const f32x4*>(Pg + (size_t)row * SS + k0 + col);
            us4 h;
            for (int jj = 0; jj < 4; ++jj) h[jj] = f2bf(wv[jj]);
            *reinterpret_cast<us4*>(&Ws[swzB(row, col)]) = h;
        }
        __syncthreads();
        for (int kk = 0; kk < 64; kk += 32) {
            short8 a[2], bv[4];
            int kcol = kk + (lg << 3);
            for (int m = 0; m < 2; ++m)
                a[m] = *reinterpret_cast<const short8*>(&Ws[swzB((wr << 5) + (m << 4) + lr, kcol)]);
            for (int n = 0; n < 4; ++n) {
                int col = (wc << 6) + (n << 4) + lr;
                const float* vp = V + ((size_t)b * SS + k0 + kcol) * DD + col;
                short8 x;
                for (int jj = 0; jj < 8; ++jj) x[jj] = (short)f2bf(vp[(size_t)jj * DD]);
                bv[n] = x;
            }
            for (int m = 0; m < 2; ++m)
                for (int n = 0; n < 4; ++n)
                    acc[m][n] = __builtin_amdgcn_mfma_f32_16x16x32_bf16(a[m], bv[n], acc[m][n], 0, 0, 0);
        }
    }
    float* Og = O + ((size_t)b * SS + m0) * DD;
    for (int m = 0; m < 2; ++m)
        for (int n = 0; n < 4; ++n)
            for (int r = 0; r < 4; ++r)
                Og[(size_t)((wr << 5) + (m << 4) + (lg << 2) + r) * DD
                   + (wc << 6) + (n << 4) + lr] = acc[m][n][r];
}

// ---------------------------------------------------------------------------
extern "C" void kernel_launch(void* const* d_in, const int* in_sizes, int n_in,
                              void* d_out, int out_size, void* d_ws, size_t ws_size,
                              hipStream_t stream)
{
    const float* Q  = (const float*)d_in[0];
    const float* K  = (const float*)d_in[1];
    const float* V  = (const float*)d_in[2];
    const int* mask = (const int*)d_in[3];
    float* O = (float*)d_out;
    float* P = O + (size_t)BB * SS * DD;

    const size_t nE = (size_t)BB * SS * DD;   // 4194304 elements per tensor
    const size_t need_base = 3 * nE * sizeof(unsigned short)
                           + 3 * (size_t)BB * SS * sizeof(float) + 256;
    const size_t need_big  = need_base + 2 * nE * sizeof(float);

    if (ws_size >= need_base) {
        unsigned short* Qb = (unsigned short*)d_ws;
        unsigned short* Kb = Qb + nE;
        unsigned short* VT = Kb + nE;
        float* maskAdd = (float*)(VT + nE);
        float* Lp      = maskAdd + (size_t)BB * SS;   // 2 * BB*SS

        prep_kernel<<<dim3(SS / 64, BB), 256, 0, stream>>>(Q, K, V, mask, Qb, Kb, VT, maskAdd);

        if (ws_size >= need_big) {
            // partials in ws -> balanced combine folded into pstore
            float* Op0 = Lp + 2 * (size_t)BB * SS;
            float* Op1 = Op0 + nE;
            flashA_kernel<<<512, 256, 0, stream>>>(Qb, Kb, VT, maskAdd, Op0, Op1, Lp);
            pstore_kernel<true><<<1024, 256, 0, stream>>>(Qb, Kb, maskAdd, Lp, P, Op0, Op1, O);
        } else {
            // partials in P region -> separate combine between flashA and pstore
            float* Op0 = P;
            float* Op1 = P + nE;
            flashA_kernel<<<512, 256, 0, stream>>>(Qb, Kb, VT, maskAdd, Op0, Op1, Lp);
            combine_kernel<<<4096, 256, 0, stream>>>(Op0, Op1, Lp, O);
            pstore_kernel<false><<<1024, 256, 0, stream>>>(Qb, Kb, maskAdd, Lp, P,
                                                           nullptr, nullptr, nullptr);
        }
    } else {
        qk_exp_kernel<<<dim3(SS / 128, SS / 128, BB), 256, 0, stream>>>(Q, K, mask, P);
        norm_kernel<<<(BB * SS) / 4, 256, 0, stream>>>(P);
        pv_fallback_kernel<<<dim3(SS / 64, BB), 256, 0, stream>>>(P, V, O);
    }
}

// Round 11
// 137.180 us; speedup vs baseline: 1.6865x; 1.0523x over previous
//
#include <hip/hip_runtime.h>

#define BB 16
#define SS 2048
#define DD 128
// exp(s/sqrt(128)) = 2^(s * CE),  CE = log2(e)/sqrt(128)
#define CE (0.08838834764831845f * 1.4426950408889634f)

typedef __attribute__((ext_vector_type(4))) float f32x4;
typedef __attribute__((ext_vector_type(8))) short short8;
typedef __attribute__((ext_vector_type(4))) unsigned short us4;
typedef __attribute__((ext_vector_type(8))) unsigned short us8;

__device__ inline unsigned short f2bf(float f) {
    unsigned u = __float_as_uint(f);
    u += 0x7fffu + ((u >> 16) & 1u);   // round-to-nearest-even
    return (unsigned short)(u >> 16);
}

// XOR swizzles (swzA: 256B rows; swzB: 128B rows)
__device__ inline int swzA(int row, int col) {
    int byteoff = (row << 8) + ((col >> 3) << 4);
    byteoff ^= (row & 7) << 4;
    return (byteoff >> 1) + (col & 7);
}
__device__ inline int swzB(int row, int col) {
    int byteoff = (row << 7) + ((col >> 3) << 4);
    byteoff ^= (row & 7) << 4;
    return (byteoff >> 1) + (col & 7);
}

// ---------------------------------------------------------------------------
// prep: Q,K fp32 -> bf16; mask -> additive fp32 (0/-inf); V -> VT bf16.
// grid (S/64, B), 256 thr.
// ---------------------------------------------------------------------------
__global__ __launch_bounds__(256) void prep_kernel(
    const float* __restrict__ Q, const float* __restrict__ K,
    const float* __restrict__ V, const int* __restrict__ mask,
    unsigned short* __restrict__ Qb, unsigned short* __restrict__ Kb,
    unsigned short* __restrict__ VT, float* __restrict__ maskAdd)
{
    __shared__ unsigned short tile[64 * 136];
    int b = blockIdx.y, k0 = blockIdx.x << 6;
    int t = threadIdx.x;
    const size_t base = ((size_t)b * SS + k0) * DD;   // 8192 elements

    for (int i = 0; i < 8; ++i) {
        int f4 = (i << 8) + t;
        f32x4 q = reinterpret_cast<const f32x4*>(Q + base)[f4];
        f32x4 k = reinterpret_cast<const f32x4*>(K + base)[f4];
        us4 qh, kh;
        for (int j = 0; j < 4; ++j) { qh[j] = f2bf(q[j]); kh[j] = f2bf(k[j]); }
        reinterpret_cast<us4*>(Qb + base)[f4] = qh;
        reinterpret_cast<us4*>(Kb + base)[f4] = kh;
    }
    if (t < 64)
        maskAdd[(size_t)b * SS + k0 + t] =
            mask[(size_t)b * SS + k0 + t] ? 0.0f : __int_as_float(0xff800000);

    for (int i = 0; i < 8; ++i) {
        int f4 = (i << 8) + t;
        int k  = f4 >> 5;
        int n  = (f4 & 31) << 2;
        f32x4 v = reinterpret_cast<const f32x4*>(V + base)[f4];
        us4 h;
        for (int j = 0; j < 4; ++j) h[j] = f2bf(v[j]);
        *reinterpret_cast<us4*>(&tile[k * 136 + n]) = h;
    }
    __syncthreads();
    unsigned short* outp = VT + (size_t)b * DD * SS;
    for (int i = 0; i < 4; ++i) {
        int id = (i << 8) + t;
        int n  = id >> 3;
        int c8 = id & 7;
        us8 o;
        for (int j = 0; j < 8; ++j) o[j] = tile[((c8 << 3) + j) * 136 + n];
        *reinterpret_cast<us8*>(&outp[(size_t)n * SS + k0 + (c8 << 3)]) = o;
    }
}

// ---------------------------------------------------------------------------
// fused: one block = (b, 64 q-rows), full KV range, 256 thr (4 waves x 16 q),
// grid 512 (2 blocks/CU, XCD batch-grouped). LDS 72KB.
// Pass A: dbuf tiles {QK^T, exp2, rowsum, P-stash, PV}; epilogue writes
//   normalized O, keeps lil = -log2(L) in-register (lane's q-row = lr).
// Pass B: re-stage K (L2-hot, dbuf), recompute S bit-identically, stream
//   P = 2^(s*CE + maskAdd + lil). No partials, no combine, no Lp.
// ---------------------------------------------------------------------------
__global__ __launch_bounds__(256, 2) void fused_kernel(
    const unsigned short* __restrict__ Qb, const unsigned short* __restrict__ Kb,
    const unsigned short* __restrict__ VT, const float* __restrict__ maskAdd,
    float* __restrict__ O, float* __restrict__ P)
{
    __shared__ unsigned short Ks[2][64 * 128];    // 2 x 16 KB
    __shared__ unsigned short VTs[2][128 * 64];   // 2 x 16 KB
    __shared__ unsigned short Ps[4 * 1024];       // per-wave 16q x 64kv (2 KB)

    const int id = blockIdx.x;
    const int xcd = id & 7, j = id >> 3;          // grid 512: j in 0..63
    const int b   = (xcd << 1) | (j >> 5);
    const int q0  = (j & 31) << 6;                // 64-row q block

    const int t = threadIdx.x, lane = t & 63, w = t >> 6;
    const int lr = lane & 15, lg = lane >> 4;

    const unsigned short* Kbb = Kb + (size_t)b * SS * DD;
    const unsigned short* Vbb = VT + (size_t)b * DD * SS;
    const float* Mb = maskAdd + (size_t)b * SS;

    // Q fragments (B-operand): q = q0 + w*16 + lr
    const unsigned short* Qp = Qb + ((size_t)b * SS + q0 + w * 16 + lr) * DD;
    short8 qf[4];
    for (int kb = 0; kb < 4; ++kb)
        qf[kb] = *reinterpret_cast<const short8*>(Qp + kb * 32 + lg * 8);

    f32x4 oacc[8] = {};
    float rsum = 0.f;
    unsigned short* Pw = &Ps[w * 1024];

    us8 kstg[4], vstg[4];
#define LOADTILE(kv)                                                             \
    for (int i = 0; i < 4; ++i) {                                                \
        int f = i * 256 + t;                                                     \
        kstg[i] = *reinterpret_cast<const us8*>(                                 \
            Kbb + (size_t)((kv) + (f >> 4)) * DD + ((f & 15) << 3));             \
        vstg[i] = *reinterpret_cast<const us8*>(                                 \
            Vbb + (size_t)(f >> 3) * SS + (kv) + ((f & 7) << 3));                \
    }
#define WRITETILE(bf)                                                            \
    for (int i = 0; i < 4; ++i) {                                                \
        int f = i * 256 + t;                                                     \
        *reinterpret_cast<us8*>(&Ks[bf][swzA(f >> 4, (f & 15) << 3)]) = kstg[i]; \
        *reinterpret_cast<us8*>(&VTs[bf][swzB(f >> 3, (f & 7) << 3)]) = vstg[i]; \
    }
#define LOADK(kv)                                                                \
    for (int i = 0; i < 4; ++i) {                                                \
        int f = i * 256 + t;                                                     \
        kstg[i] = *reinterpret_cast<const us8*>(                                 \
            Kbb + (size_t)((kv) + (f >> 4)) * DD + ((f & 15) << 3));             \
    }
#define WRITEK(bf)                                                               \
    for (int i = 0; i < 4; ++i) {                                                \
        int f = i * 256 + t;                                                     \
        *reinterpret_cast<us8*>(&Ks[bf][swzA(f >> 4, (f & 15) << 3)]) = kstg[i]; \
    }

    // ---------------- pass A ----------------
    LOADTILE(0);
    WRITETILE(0);

    for (int kt = 0; kt < 32; ++kt) {
        const int cur = kt & 1;
        const int kv0 = kt << 6;
        if (kt + 1 < 32) { LOADTILE(kv0 + 64); }   // T14
        __syncthreads();                           // buf[cur] visible

        // S^T = K . Q^T : S[kv=n*16+lg*4+r][q=lr] — order identical to pass B
        f32x4 sacc[4] = {};
        __builtin_amdgcn_s_setprio(1);
        for (int kb = 0; kb < 4; ++kb) {
            short8 kf[4];
            for (int n = 0; n < 4; ++n)
                kf[n] = *reinterpret_cast<const short8*>(
                    &Ks[cur][swzA(n * 16 + lr, kb * 32 + lg * 8)]);
            for (int n = 0; n < 4; ++n)
                sacc[n] = __builtin_amdgcn_mfma_f32_16x16x32_bf16(
                    kf[n], qf[kb], sacc[n], 0, 0, 0);
        }
        __builtin_amdgcn_s_setprio(0);

        // p = 2^(s*CE + ma); rowsum; stash bf16 P[q=lr][kv]
        for (int n = 0; n < 4; ++n) {
            f32x4 ma = *reinterpret_cast<const f32x4*>(Mb + kv0 + n * 16 + lg * 4);
            us4 hh;
            for (int r = 0; r < 4; ++r) {
                float p = __builtin_amdgcn_exp2f(fmaf(sacc[n][r], CE, ma[r]));
                rsum += p;
                hh[r] = f2bf(p);
            }
            *reinterpret_cast<us4*>(&Pw[swzB(lr, n * 16 + lg * 4)]) = hh;
        }
        asm volatile("s_waitcnt lgkmcnt(0)" ::: "memory");
        __builtin_amdgcn_sched_barrier(0);

        // O += P*V
        __builtin_amdgcn_s_setprio(1);
        for (int kb2 = 0; kb2 < 2; ++kb2) {
            short8 pf = *reinterpret_cast<const short8*>(&Pw[swzB(lr, kb2 * 32 + lg * 8)]);
            for (int nd = 0; nd < 8; ++nd) {
                short8 vf = *reinterpret_cast<const short8*>(
                    &VTs[cur][swzB(nd * 16 + lr, kb2 * 32 + lg * 8)]);
                oacc[nd] = __builtin_amdgcn_mfma_f32_16x16x32_bf16(pf, vf, oacc[nd], 0, 0, 0);
            }
        }
        __builtin_amdgcn_s_setprio(0);

        if (kt + 1 < 32) { WRITETILE(cur ^ 1); }   // readers passed barrier above
    }

    // reduce L across lg groups (lane holds q-row = lr)
    rsum += __shfl_xor(rsum, 16, 64);
    rsum += __shfl_xor(rsum, 32, 64);

    // epilogue: O = oacc / L (element r belongs to q-row lg*4+r)
    {
        f32x4 invq;
        for (int r = 0; r < 4; ++r) {
            float Lq = __shfl(rsum, 4 * lg + r, 64);
            invq[r] = Lq > 0.f ? 1.f / Lq : 0.f;
        }
        float* Og = O + ((size_t)b * SS + q0 + w * 16) * DD;
        for (int nd = 0; nd < 8; ++nd)
            for (int r = 0; r < 4; ++r)
                Og[(size_t)(lg * 4 + r) * DD + nd * 16 + lr] = oacc[nd][r] * invq[r];
    }
    const float lil = rsum > 0.f ? -__builtin_amdgcn_logf(rsum)
                                 : __int_as_float(0xff800000);

    // ---------------- pass B ----------------
    LOADK(0);
    WRITEK(0);   // safe: Ks[0] last read at kt=30, all waves past kt=31 barrier

    for (int kt = 0; kt < 32; ++kt) {
        const int cur = kt & 1;
        const int kv0 = kt << 6;
        if (kt + 1 < 32) { LOADK(kv0 + 64); }
        __syncthreads();   // WRITEK(cur) visible; first iter also fences pass A

        // identical structure/order to pass A -> bit-identical sacc
        f32x4 sacc[4] = {};
        for (int kb = 0; kb < 4; ++kb) {
            short8 kf[4];
            for (int n = 0; n < 4; ++n)
                kf[n] = *reinterpret_cast<const short8*>(
                    &Ks[cur][swzA(n * 16 + lr, kb * 32 + lg * 8)]);
            for (int n = 0; n < 4; ++n)
                sacc[n] = __builtin_amdgcn_mfma_f32_16x16x32_bf16(
                    kf[n], qf[kb], sacc[n], 0, 0, 0);
        }

        float* Pp = P + ((size_t)b * SS + q0 + w * 16 + lr) * SS + kv0;
        for (int n = 0; n < 4; ++n) {
            f32x4 ma = *reinterpret_cast<const f32x4*>(Mb + kv0 + n * 16 + lg * 4);
            f32x4 out;
            for (int r = 0; r < 4; ++r)
                out[r] = __builtin_amdgcn_exp2f(fmaf(sacc[n][r], CE, ma[r]) + lil);
            *reinterpret_cast<f32x4*>(Pp + n * 16 + lg * 4) = out;
        }

        if (kt + 1 < 32) { WRITEK(cur ^ 1); }
    }
#undef LOADTILE
#undef WRITETILE
#undef LOADK
#undef WRITEK
}

// ---------------------------------------------------------------------------
// Fallback pipeline (no workspace requirements)
// ---------------------------------------------------------------------------
__global__ __launch_bounds__(256) void qk_exp_kernel(
    const float* __restrict__ Q, const float* __restrict__ Kin,
    const int* __restrict__ mask, float* __restrict__ P)
{
    __shared__ unsigned short Qs[128 * 128];
    __shared__ unsigned short Ks[128 * 128];
    const int b  = blockIdx.z;
    const int m0 = blockIdx.y << 7;
    const int n0 = blockIdx.x << 7;
    const int t  = threadIdx.x;
    const float* Qp = Q   + ((size_t)b * SS + m0) * DD;
    const float* Kp = Kin + ((size_t)b * SS + n0) * DD;
    for (int i = 0; i < 16; ++i) {
        int f4  = (i << 8) + t;
        int row = f4 >> 5;
        int col = (f4 & 31) << 2;
        f32x4 q = reinterpret_cast<const f32x4*>(Qp)[f4];
        f32x4 k = reinterpret_cast<const f32x4*>(Kp)[f4];
        us4 qh, kh;
        for (int jj = 0; jj < 4; ++jj) { qh[jj] = f2bf(q[jj]); kh[jj] = f2bf(k[jj]); }
        *reinterpret_cast<us4*>(&Qs[swzA(row, col)]) = qh;
        *reinterpret_cast<us4*>(&Ks[swzA(row, col)]) = kh;
    }
    __syncthreads();
    const int lane = t & 63, wid = t >> 6;
    const int wr = wid >> 1, wc = wid & 1;
    const int lr = lane & 15, lg = lane >> 4;
    f32x4 acc[4][4] = {};
    for (int kb = 0; kb < 4; ++kb) {
        short8 a[4], bq[4];
        int kcol = (kb << 5) + (lg << 3);
        for (int m = 0; m < 4; ++m)
            a[m] = *reinterpret_cast<const short8*>(&Qs[swzA((wr << 6) + (m << 4) + lr, kcol)]);
        for (int n = 0; n < 4; ++n)
            bq[n] = *reinterpret_cast<const short8*>(&Ks[swzA((wc << 6) + (n << 4) + lr, kcol)]);
        for (int m = 0; m < 4; ++m)
            for (int n = 0; n < 4; ++n)
                acc[m][n] = __builtin_amdgcn_mfma_f32_16x16x32_bf16(a[m], bq[n], acc[m][n], 0, 0, 0);
    }
    const int* am = mask + (size_t)b * SS;
    for (int n = 0; n < 4; ++n) {
        int col = n0 + (wc << 6) + (n << 4) + lr;
        bool allow = am[col] != 0;
        for (int m = 0; m < 4; ++m) {
            int rowb = m0 + (wr << 6) + (m << 4) + (lg << 2);
            float* Pp = P + ((size_t)b * SS + rowb) * SS + col;
            for (int r = 0; r < 4; ++r) {
                float p = allow ? __expf(acc[m][n][r] * 0.08838834764831845f) : 0.0f;
                Pp[(size_t)r * SS] = p;
            }
        }
    }
}

__global__ __launch_bounds__(256) void norm_kernel(float* __restrict__ P)
{
    int row  = (blockIdx.x << 2) + (threadIdx.x >> 6);
    int lane = threadIdx.x & 63;
    float* Pr = P + (size_t)row * SS;
    f32x4 v[8];
    float sum = 0.f;
    for (int i = 0; i < 8; ++i) {
        v[i] = reinterpret_cast<f32x4*>(Pr)[(i << 6) + lane];
        sum += v[i][0] + v[i][1] + v[i][2] + v[i][3];
    }
    for (int off = 1; off < 64; off <<= 1) sum += __shfl_xor(sum, off, 64);
    float inv = sum > 0.f ? 1.f / sum : 0.f;
    for (int i = 0; i < 8; ++i) {
        f32x4 wv = v[i];
        for (int jj = 0; jj < 4; ++jj) wv[jj] *= inv;
        reinterpret_cast<f32x4*>(Pr)[(i << 6) + lane] = wv;
    }
}

__global__ __launch_bounds__(256) void pv_fallback_kernel(
    const float* __restrict__ P, const float* __restrict__ V, float* __restrict__ O)
{
    __shared__ unsigned short Ws[64 * 64];
    const int b  = blockIdx.y;
    const int m0 = blockIdx.x << 6;
    const int t  = threadIdx.x, lane = t & 63, wid = t >> 6;
    const int wr = wid >> 1, wc = wid & 1;
    const int lr = lane & 15, lg = lane >> 4;
    const float* Pg = P + ((size_t)b * SS + m0) * SS;
    f32x4 acc[2][4] = {};
    for (int k0 = 0; k0 < SS; k0 += 64) {
        __syncthreads();
        for (int i = 0; i < 4; ++i) {
            int f4  = (i << 8) + t;
            int row = f4 >> 4;
            int col = (f4 & 15) << 2;
            f32x4 wv = *reinterpret_cast<const f32x4*>(Pg + (size_t)row * SS + k0 + col);
            us4 h;
            for (int jj = 0; jj < 4; ++jj) h[jj] = f2bf(wv[jj]);
            *reinterpret_cast<us4*>(&Ws[swzB(row, col)]) = h;
        }
        __syncthreads();
        for (int kk = 0; kk < 64; kk += 32) {
            short8 a[2], bv[4];
            int kcol = kk + (lg << 3);
            for (int m = 0; m < 2; ++m)
                a[m] = *reinterpret_cast<const short8*>(&Ws[swzB((wr << 5) + (m << 4) + lr, kcol)]);
            for (int n = 0; n < 4; ++n) {
                int col = (wc << 6) + (n << 4) + lr;
                const float* vp = V + ((size_t)b * SS + k0 + kcol) * DD + col;
                short8 x;
                for (int jj = 0; jj < 8; ++jj) x[jj] = (short)f2bf(vp[(size_t)jj * DD]);
                bv[n] = x;
            }
            for (int m = 0; m < 2; ++m)
                for (int n = 0; n < 4; ++n)
                    acc[m][n] = __builtin_amdgcn_mfma_f32_16x16x32_bf16(a[m], bv[n], acc[m][n], 0, 0, 0);
        }
    }
    float* Og = O + ((size_t)b * SS + m0) * DD;
    for (int m = 0; m < 2; ++m)
        for (int n = 0; n < 4; ++n)
            for (int r = 0; r < 4; ++r)
                Og[(size_t)((wr << 5) + (m << 4) + (lg << 2) + r) * DD
                   + (wc << 6) + (n << 4) + lr] = acc[m][n][r];
}

// ---------------------------------------------------------------------------
extern "C" void kernel_launch(void* const* d_in, const int* in_sizes, int n_in,
                              void* d_out, int out_size, void* d_ws, size_t ws_size,
                              hipStream_t stream)
{
    const float* Q  = (const float*)d_in[0];
    const float* K  = (const float*)d_in[1];
    const float* V  = (const float*)d_in[2];
    const int* mask = (const int*)d_in[3];
    float* O = (float*)d_out;
    float* P = O + (size_t)BB * SS * DD;

    const size_t nE = (size_t)BB * SS * DD;   // 4194304 elements per tensor
    const size_t need = 3 * nE * sizeof(unsigned short)
                      + (size_t)BB * SS * sizeof(float) + 256;

    if (ws_size >= need) {
        unsigned short* Qb = (unsigned short*)d_ws;
        unsigned short* Kb = Qb + nE;
        unsigned short* VT = Kb + nE;
        float* maskAdd = (float*)(VT + nE);

        prep_kernel<<<dim3(SS / 64, BB), 256, 0, stream>>>(Q, K, V, mask, Qb, Kb, VT, maskAdd);
        fused_kernel<<<512, 256, 0, stream>>>(Qb, Kb, VT, maskAdd, O, P);
    } else {
        qk_exp_kernel<<<dim3(SS / 128, SS / 128, BB), 256, 0, stream>>>(Q, K, mask, P);
        norm_kernel<<<(BB * SS) / 4, 256, 0, stream>>>(P);
        pv_fallback_kernel<<<dim3(SS / 64, BB), 256, 0, stream>>>(P, V, O);
    }
}

// Round 12
// 133.827 us; speedup vs baseline: 1.7287x; 1.0251x over previous
//
#include <hip/hip_runtime.h>

#define BB 16
#define SS 2048
#define DD 128
// exp(s/sqrt(128)) = 2^(s * CE),  CE = log2(e)/sqrt(128)
#define CE (0.08838834764831845f * 1.4426950408889634f)

typedef __attribute__((ext_vector_type(4))) float f32x4;
typedef __attribute__((ext_vector_type(8))) short short8;
typedef __attribute__((ext_vector_type(4))) unsigned short us4;
typedef __attribute__((ext_vector_type(8))) unsigned short us8;

__device__ inline unsigned short f2bf(float f) {
    unsigned u = __float_as_uint(f);
    u += 0x7fffu + ((u >> 16) & 1u);   // round-to-nearest-even
    return (unsigned short)(u >> 16);
}

// XOR swizzles (swzA: 256B rows; swzB: 128B rows)
__device__ inline int swzA(int row, int col) {
    int byteoff = (row << 8) + ((col >> 3) << 4);
    byteoff ^= (row & 7) << 4;
    return (byteoff >> 1) + (col & 7);
}
__device__ inline int swzB(int row, int col) {
    int byteoff = (row << 7) + ((col >> 3) << 4);
    byteoff ^= (row & 7) << 4;
    return (byteoff >> 1) + (col & 7);
}

// ---------------------------------------------------------------------------
// prep: Q,K fp32 -> bf16; mask -> additive fp32 (0/-inf); V -> VT bf16.
// ---------------------------------------------------------------------------
__global__ __launch_bounds__(256) void prep_kernel(
    const float* __restrict__ Q, const float* __restrict__ K,
    const float* __restrict__ V, const int* __restrict__ mask,
    unsigned short* __restrict__ Qb, unsigned short* __restrict__ Kb,
    unsigned short* __restrict__ VT, float* __restrict__ maskAdd)
{
    __shared__ unsigned short tile[64 * 136];
    int b = blockIdx.y, k0 = blockIdx.x << 6;
    int t = threadIdx.x;
    const size_t base = ((size_t)b * SS + k0) * DD;   // 8192 elements

    for (int i = 0; i < 8; ++i) {
        int f4 = (i << 8) + t;
        f32x4 q = reinterpret_cast<const f32x4*>(Q + base)[f4];
        f32x4 k = reinterpret_cast<const f32x4*>(K + base)[f4];
        us4 qh, kh;
        for (int j = 0; j < 4; ++j) { qh[j] = f2bf(q[j]); kh[j] = f2bf(k[j]); }
        reinterpret_cast<us4*>(Qb + base)[f4] = qh;
        reinterpret_cast<us4*>(Kb + base)[f4] = kh;
    }
    if (t < 64)
        maskAdd[(size_t)b * SS + k0 + t] =
            mask[(size_t)b * SS + k0 + t] ? 0.0f : __int_as_float(0xff800000);

    for (int i = 0; i < 8; ++i) {
        int f4 = (i << 8) + t;
        int k  = f4 >> 5;
        int n  = (f4 & 31) << 2;
        f32x4 v = reinterpret_cast<const f32x4*>(V + base)[f4];
        us4 h;
        for (int j = 0; j < 4; ++j) h[j] = f2bf(v[j]);
        *reinterpret_cast<us4*>(&tile[k * 136 + n]) = h;
    }
    __syncthreads();
    unsigned short* outp = VT + (size_t)b * DD * SS;
    for (int i = 0; i < 4; ++i) {
        int id = (i << 8) + t;
        int n  = id >> 3;
        int c8 = id & 7;
        us8 o;
        for (int j = 0; j < 8; ++j) o[j] = tile[((c8 << 3) + j) * 136 + n];
        *reinterpret_cast<us8*>(&outp[(size_t)n * SS + k0 + (c8 << 3)]) = o;
    }
}

// ---------------------------------------------------------------------------
// fused8: block = (b, 128 q-rows), full KV. 512 thr = 8 waves in 4x2 (wq,wkv).
// grid 256 (1 block/CU, XCD batch-grouped). LDS ~81 KB.
// Pass A: per 64-kv dbuf tile, wave handles 32q x 32kv quadrant:
//   QK^T -> exp2 -> rowsum -> P-stash -> PV. Epilogue: cross-wave (wkv pair)
//   oacc+L reduce via LDS, write normalized O, publish L in Larr.
// Pass B: 8 waves x 16 q, shared dbuf K tiles, recompute S bit-identically,
//   stream P = 2^(s*CE + maskAdd + lil).
// ---------------------------------------------------------------------------
__global__ __launch_bounds__(512, 2) void fused8_kernel(
    const unsigned short* __restrict__ Qb, const unsigned short* __restrict__ Kb,
    const unsigned short* __restrict__ VT, const float* __restrict__ maskAdd,
    float* __restrict__ O, float* __restrict__ P)
{
    __shared__ unsigned short Ks[2][64 * 128];    // 32 KB (reused as xch floats)
    __shared__ unsigned short VTs[2][128 * 64];   // 32 KB
    __shared__ unsigned short Ps[8 * 1024];       // 16 KB: per-wave 16r x 64c
    __shared__ float Lhalf[4][32];
    __shared__ float Larr[128];

    const int id = blockIdx.x;                    // grid 256
    const int xcd = id & 7, j = id >> 3;          // j in 0..31
    const int b   = (xcd << 1) | (j >> 4);
    const int q0  = (j & 15) << 7;                // 128-row q panel

    const int t = threadIdx.x, lane = t & 63, w = t >> 6;
    const int wq = w >> 1, wkv = w & 1;
    const int lr = lane & 15, lg = lane >> 4;

    const unsigned short* Kbb = Kb + (size_t)b * SS * DD;
    const unsigned short* Vbb = VT + (size_t)b * DD * SS;
    const float* Mb = maskAdd + (size_t)b * SS;

    // Pass-A Q fragments (B-operand): q = q0 + wq*32 + m*16 + lr
    const unsigned short* Qp = Qb + ((size_t)b * SS + q0 + wq * 32) * DD;
    short8 qf[2][4];
    for (int m = 0; m < 2; ++m)
        for (int kb = 0; kb < 4; ++kb)
            qf[m][kb] = *reinterpret_cast<const short8*>(
                Qp + (size_t)(m * 16 + lr) * DD + kb * 32 + lg * 8);

    f32x4 oacc[2][8] = {};
    float rsum[2] = {0.f, 0.f};
    unsigned short* Pw = &Ps[w * 1024];

    us8 kstg[2], vstg[2];
#define LOADTILE(kv)                                                             \
    for (int i = 0; i < 2; ++i) {                                                \
        int f = i * 512 + t;                                                     \
        kstg[i] = *reinterpret_cast<const us8*>(                                 \
            Kbb + (size_t)((kv) + (f >> 4)) * DD + ((f & 15) << 3));             \
        vstg[i] = *reinterpret_cast<const us8*>(                                 \
            Vbb + (size_t)(f >> 3) * SS + (kv) + ((f & 7) << 3));                \
    }
#define WRITETILE(bf)                                                            \
    for (int i = 0; i < 2; ++i) {                                                \
        int f = i * 512 + t;                                                     \
        *reinterpret_cast<us8*>(&Ks[bf][swzA(f >> 4, (f & 15) << 3)]) = kstg[i]; \
        *reinterpret_cast<us8*>(&VTs[bf][swzB(f >> 3, (f & 7) << 3)]) = vstg[i]; \
    }
#define LOADK(kv)                                                                \
    for (int i = 0; i < 2; ++i) {                                                \
        int f = i * 512 + t;                                                     \
        kstg[i] = *reinterpret_cast<const us8*>(                                 \
            Kbb + (size_t)((kv) + (f >> 4)) * DD + ((f & 15) << 3));             \
    }
#define WRITEK(bf)                                                               \
    for (int i = 0; i < 2; ++i) {                                                \
        int f = i * 512 + t;                                                     \
        *reinterpret_cast<us8*>(&Ks[bf][swzA(f >> 4, (f & 15) << 3)]) = kstg[i]; \
    }

    // ---------------- pass A ----------------
    LOADTILE(0);
    WRITETILE(0);

    for (int kt = 0; kt < 32; ++kt) {
        const int cur = kt & 1;
        const int kv0 = kt << 6;
        if (kt + 1 < 32) { LOADTILE(kv0 + 64); }   // T14
        __syncthreads();                           // buf[cur] visible

        // S^T quadrant: rows kv = wkv*32 + n*16 + lg*4 + r, cols q = m*16+lr
        f32x4 sacc[2][2] = {};
        __builtin_amdgcn_s_setprio(1);
        for (int kb = 0; kb < 4; ++kb) {
            short8 kf[2];
            for (int n = 0; n < 2; ++n)
                kf[n] = *reinterpret_cast<const short8*>(
                    &Ks[cur][swzA(wkv * 32 + n * 16 + lr, kb * 32 + lg * 8)]);
            for (int n = 0; n < 2; ++n)
                for (int m = 0; m < 2; ++m)
                    sacc[m][n] = __builtin_amdgcn_mfma_f32_16x16x32_bf16(
                        kf[n], qf[m][kb], sacc[m][n], 0, 0, 0);
        }
        __builtin_amdgcn_s_setprio(0);

        // p = 2^(s*CE + ma); rowsum; stash P[q=m*16+lr][kv_local] at (lr, m*32+kv)
        for (int n = 0; n < 2; ++n) {
            f32x4 ma = *reinterpret_cast<const f32x4*>(
                Mb + kv0 + wkv * 32 + n * 16 + lg * 4);
            for (int m = 0; m < 2; ++m) {
                us4 hh;
                for (int r = 0; r < 4; ++r) {
                    float p = __builtin_amdgcn_exp2f(fmaf(sacc[m][n][r], CE, ma[r]));
                    rsum[m] += p;
                    hh[r] = f2bf(p);
                }
                *reinterpret_cast<us4*>(&Pw[swzB(lr, m * 32 + n * 16 + lg * 4)]) = hh;
            }
        }
        asm volatile("s_waitcnt lgkmcnt(0)" ::: "memory");
        __builtin_amdgcn_sched_barrier(0);

        // PV over the 32-kv quadrant (single K=32 step)
        short8 pf[2];
        for (int m = 0; m < 2; ++m)
            pf[m] = *reinterpret_cast<const short8*>(&Pw[swzB(lr, m * 32 + lg * 8)]);
        __builtin_amdgcn_s_setprio(1);
        for (int nd = 0; nd < 8; ++nd) {
            short8 vf = *reinterpret_cast<const short8*>(
                &VTs[cur][swzB(nd * 16 + lr, wkv * 32 + lg * 8)]);
            for (int m = 0; m < 2; ++m)
                oacc[m][nd] = __builtin_amdgcn_mfma_f32_16x16x32_bf16(
                    pf[m], vf, oacc[m][nd], 0, 0, 0);
        }
        __builtin_amdgcn_s_setprio(0);

        if (kt + 1 < 32) { WRITETILE(cur ^ 1); }   // readers passed top barrier
    }

    // ---------------- epilogue: cross-wave reduce + O write ----------------
    for (int m = 0; m < 2; ++m) {   // sum over lg groups (q = ... + lr)
        rsum[m] += __shfl_xor(rsum[m], 16, 64);
        rsum[m] += __shfl_xor(rsum[m], 32, 64);
    }
    __syncthreads();   // pass A fully done; Ks reusable as xch
    if (wkv == 1 && lg == 0)
        for (int m = 0; m < 2; ++m) Lhalf[wq][m * 16 + lr] = rsum[m];
    __syncthreads();
    if (wkv == 0) {
        for (int m = 0; m < 2; ++m) {
            float L = rsum[m] + Lhalf[wq][m * 16 + lr];
            if (lg == 0) Larr[wq * 32 + m * 16 + lr] = L;
        }
    }
    // oacc exchange in 2 rounds through the Ks region (32 KB = 8192 floats)
    float* xch = reinterpret_cast<float*>(&Ks[0][0]);
    for (int round = 0; round < 2; ++round) {
        __syncthreads();
        if (wkv == 1 && (wq >> 1) == round)
            for (int m = 0; m < 2; ++m)
                for (int nd = 0; nd < 8; ++nd)
                    for (int r = 0; r < 4; ++r)
                        xch[(wq & 1) * 4096 + (m * 16 + lg * 4 + r) * 128 + nd * 16 + lr]
                            = oacc[m][nd][r];
        __syncthreads();
        if (wkv == 0 && (wq >> 1) == round)
            for (int m = 0; m < 2; ++m)
                for (int nd = 0; nd < 8; ++nd)
                    for (int r = 0; r < 4; ++r)
                        oacc[m][nd][r] +=
                            xch[(wq & 1) * 4096 + (m * 16 + lg * 4 + r) * 128 + nd * 16 + lr];
    }
    __syncthreads();   // Larr + exchange complete
    if (wkv == 0) {
        float* Og = O + ((size_t)b * SS + q0 + wq * 32) * DD;
        float inv[2][4];
        for (int m = 0; m < 2; ++m)
            for (int r = 0; r < 4; ++r) {
                float L = Larr[wq * 32 + m * 16 + lg * 4 + r];
                inv[m][r] = L > 0.f ? 1.f / L : 0.f;
            }
        for (int m = 0; m < 2; ++m)
            for (int nd = 0; nd < 8; ++nd)
                for (int r = 0; r < 4; ++r)
                    Og[(size_t)(m * 16 + lg * 4 + r) * DD + nd * 16 + lr]
                        = oacc[m][nd][r] * inv[m][r];
    }
    __syncthreads();

    // pass-B per-row lil (q = w*16 + lr)
    float Lq = Larr[w * 16 + lr];
    const float lil = Lq > 0.f ? -__builtin_amdgcn_logf(Lq)
                               : __int_as_float(0xff800000);
    short8 qf2[4];
    {
        const unsigned short* Qp2 = Qb + ((size_t)b * SS + q0 + w * 16 + lr) * DD;
        for (int kb = 0; kb < 4; ++kb)
            qf2[kb] = *reinterpret_cast<const short8*>(Qp2 + kb * 32 + lg * 8);
    }

    // ---------------- pass B ----------------
    LOADK(0);
    WRITEK(0);   // safe: all exchange reads done before last barrier

    for (int kt = 0; kt < 32; ++kt) {
        const int cur = kt & 1;
        const int kv0 = kt << 6;
        if (kt + 1 < 32) { LOADK(kv0 + 64); }
        __syncthreads();

        // identical per-(q,kv) kb-chain as pass A -> bit-identical S
        f32x4 sacc2[4] = {};
        for (int kb = 0; kb < 4; ++kb) {
            short8 kf[4];
            for (int n = 0; n < 4; ++n)
                kf[n] = *reinterpret_cast<const short8*>(
                    &Ks[cur][swzA(n * 16 + lr, kb * 32 + lg * 8)]);
            for (int n = 0; n < 4; ++n)
                sacc2[n] = __builtin_amdgcn_mfma_f32_16x16x32_bf16(
                    kf[n], qf2[kb], sacc2[n], 0, 0, 0);
        }

        float* Pp = P + ((size_t)b * SS + q0 + w * 16 + lr) * SS + kv0;
        for (int n = 0; n < 4; ++n) {
            f32x4 ma = *reinterpret_cast<const f32x4*>(Mb + kv0 + n * 16 + lg * 4);
            f32x4 out;
            for (int r = 0; r < 4; ++r)
                out[r] = __builtin_amdgcn_exp2f(fmaf(sacc2[n][r], CE, ma[r]) + lil);
            *reinterpret_cast<f32x4*>(Pp + n * 16 + lg * 4) = out;
        }

        if (kt + 1 < 32) { WRITEK(cur ^ 1); }
    }
#undef LOADTILE
#undef WRITETILE
#undef LOADK
#undef WRITEK
}

// ---------------------------------------------------------------------------
// Fallback pipeline (no workspace requirements)
// ---------------------------------------------------------------------------
__global__ __launch_bounds__(256) void qk_exp_kernel(
    const float* __restrict__ Q, const float* __restrict__ Kin,
    const int* __restrict__ mask, float* __restrict__ P)
{
    __shared__ unsigned short Qs[128 * 128];
    __shared__ unsigned short Ks[128 * 128];
    const int b  = blockIdx.z;
    const int m0 = blockIdx.y << 7;
    const int n0 = blockIdx.x << 7;
    const int t  = threadIdx.x;
    const float* Qp = Q   + ((size_t)b * SS + m0) * DD;
    const float* Kp = Kin + ((size_t)b * SS + n0) * DD;
    for (int i = 0; i < 16; ++i) {
        int f4  = (i << 8) + t;
        int row = f4 >> 5;
        int col = (f4 & 31) << 2;
        f32x4 q = reinterpret_cast<const f32x4*>(Qp)[f4];
        f32x4 k = reinterpret_cast<const f32x4*>(Kp)[f4];
        us4 qh, kh;
        for (int jj = 0; jj < 4; ++jj) { qh[jj] = f2bf(q[jj]); kh[jj] = f2bf(k[jj]); }
        *reinterpret_cast<us4*>(&Qs[swzA(row, col)]) = qh;
        *reinterpret_cast<us4*>(&Ks[swzA(row, col)]) = kh;
    }
    __syncthreads();
    const int lane = t & 63, wid = t >> 6;
    const int wr = wid >> 1, wc = wid & 1;
    const int lr = lane & 15, lg = lane >> 4;
    f32x4 acc[4][4] = {};
    for (int kb = 0; kb < 4; ++kb) {
        short8 a[4], bq[4];
        int kcol = (kb << 5) + (lg << 3);
        for (int m = 0; m < 4; ++m)
            a[m] = *reinterpret_cast<const short8*>(&Qs[swzA((wr << 6) + (m << 4) + lr, kcol)]);
        for (int n = 0; n < 4; ++n)
            bq[n] = *reinterpret_cast<const short8*>(&Ks[swzA((wc << 6) + (n << 4) + lr, kcol)]);
        for (int m = 0; m < 4; ++m)
            for (int n = 0; n < 4; ++n)
                acc[m][n] = __builtin_amdgcn_mfma_f32_16x16x32_bf16(a[m], bq[n], acc[m][n], 0, 0, 0);
    }
    const int* am = mask + (size_t)b * SS;
    for (int n = 0; n < 4; ++n) {
        int col = n0 + (wc << 6) + (n << 4) + lr;
        bool allow = am[col] != 0;
        for (int m = 0; m < 4; ++m) {
            int rowb = m0 + (wr << 6) + (m << 4) + (lg << 2);
            float* Pp = P + ((size_t)b * SS + rowb) * SS + col;
            for (int r = 0; r < 4; ++r) {
                float p = allow ? __expf(acc[m][n][r] * 0.08838834764831845f) : 0.0f;
                Pp[(size_t)r * SS] = p;
            }
        }
    }
}

__global__ __launch_bounds__(256) void norm_kernel(float* __restrict__ P)
{
    int row  = (blockIdx.x << 2) + (threadIdx.x >> 6);
    int lane = threadIdx.x & 63;
    float* Pr = P + (size_t)row * SS;
    f32x4 v[8];
    float sum = 0.f;
    for (int i = 0; i < 8; ++i) {
        v[i] = reinterpret_cast<f32x4*>(Pr)[(i << 6) + lane];
        sum += v[i][0] + v[i][1] + v[i][2] + v[i][3];
    }
    for (int off = 1; off < 64; off <<= 1) sum += __shfl_xor(sum, off, 64);
    float inv = sum > 0.f ? 1.f / sum : 0.f;
    for (int i = 0; i < 8; ++i) {
        f32x4 wv = v[i];
        for (int jj = 0; jj < 4; ++jj) wv[jj] *= inv;
        reinterpret_cast<f32x4*>(Pr)[(i << 6) + lane] = wv;
    }
}

__global__ __launch_bounds__(256) void pv_fallback_kernel(
    const float* __restrict__ P, const float* __restrict__ V, float* __restrict__ O)
{
    __shared__ unsigned short Ws[64 * 64];
    const int b  = blockIdx.y;
    const int m0 = blockIdx.x << 6;
    const int t  = threadIdx.x, lane = t & 63, wid = t >> 6;
    const int wr = wid >> 1, wc = wid & 1;
    const int lr = lane & 15, lg = lane >> 4;
    const float* Pg = P + ((size_t)b * SS + m0) * SS;
    f32x4 acc[2][4] = {};
    for (int k0 = 0; k0 < SS; k0 += 64) {
        __syncthreads();
        for (int i = 0; i < 4; ++i) {
            int f4  = (i << 8) + t;
            int row = f4 >> 4;
            int col = (f4 & 15) << 2;
            f32x4 wv = *reinterpret_cast<const f32x4*>(Pg + (size_t)row * SS + k0 + col);
            us4 h;
            for (int jj = 0; jj < 4; ++jj) h[jj] = f2bf(wv[jj]);
            *reinterpret_cast<us4*>(&Ws[swzB(row, col)]) = h;
        }
        __syncthreads();
        for (int kk = 0; kk < 64; kk += 32) {
            short8 a[2], bv[4];
            int kcol = kk + (lg << 3);
            for (int m = 0; m < 2; ++m)
                a[m] = *reinterpret_cast<const short8*>(&Ws[swzB((wr << 5) + (m << 4) + lr, kcol)]);
            for (int n = 0; n < 4; ++n) {
                int col = (wc << 6) + (n << 4) + lr;
                const float* vp = V + ((size_t)b * SS + k0 + kcol) * DD + col;
                short8 x;
                for (int jj = 0; jj < 8; ++jj) x[jj] = (short)f2bf(vp[(size_t)jj * DD]);
                bv[n] = x;
            }
            for (int m = 0; m < 2; ++m)
                for (int n = 0; n < 4; ++n)
                    acc[m][n] = __builtin_amdgcn_mfma_f32_16x16x32_bf16(a[m], bv[n], acc[m][n], 0, 0, 0);
        }
    }
    float* Og = O + ((size_t)b * SS + m0) * DD;
    for (int m = 0; m < 2; ++m)
        for (int n = 0; n < 4; ++n)
            for (int r = 0; r < 4; ++r)
                Og[(size_t)((wr << 5) + (m << 4) + (lg << 2) + r) * DD
                   + (wc << 6) + (n << 4) + lr] = acc[m][n][r];
}

// ---------------------------------------------------------------------------
extern "C" void kernel_launch(void* const* d_in, const int* in_sizes, int n_in,
                              void* d_out, int out_size, void* d_ws, size_t ws_size,
                              hipStream_t stream)
{
    const float* Q  = (const float*)d_in[0];
    const float* K  = (const float*)d_in[1];
    const float* V  = (const float*)d_in[2];
    const int* mask = (const int*)d_in[3];
    float* O = (float*)d_out;
    float* P = O + (size_t)BB * SS * DD;

    const size_t nE = (size_t)BB * SS * DD;   // 4194304 elements per tensor
    const size_t need = 3 * nE * sizeof(unsigned short)
                      + (size_t)BB * SS * sizeof(float) + 256;

    if (ws_size >= need) {
        unsigned short* Qb = (unsigned short*)d_ws;
        unsigned short* Kb = Qb + nE;
        unsigned short* VT = Kb + nE;
        float* maskAdd = (float*)(VT + nE);

        prep_kernel<<<dim3(SS / 64, BB), 256, 0, stream>>>(Q, K, V, mask, Qb, Kb, VT, maskAdd);
        fused8_kernel<<<256, 512, 0, stream>>>(Qb, Kb, VT, maskAdd, O, P);
    } else {
        qk_exp_kernel<<<dim3(SS / 128, SS / 128, BB), 256, 0, stream>>>(Q, K, mask, P);
        norm_kernel<<<(BB * SS) / 4, 256, 0, stream>>>(P);
        pv_fallback_kernel<<<dim3(SS / 64, BB), 256, 0, stream>>>(P, V, O);
    }
}

// Round 13
// 133.635 us; speedup vs baseline: 1.7312x; 1.0014x over previous
//
#include <hip/hip_runtime.h>

#define BB 16
#define SS 2048
#define DD 128
// exp(s/sqrt(128)) = 2^(s * CE),  CE = log2(e)/sqrt(128)
#define CE (0.08838834764831845f * 1.4426950408889634f)

typedef __attribute__((ext_vector_type(4))) float f32x4;
typedef __attribute__((ext_vector_type(8))) short short8;
typedef __attribute__((ext_vector_type(4))) unsigned short us4;
typedef __attribute__((ext_vector_type(8))) unsigned short us8;

__device__ inline unsigned short f2bf(float f) {
    unsigned u = __float_as_uint(f);
    u += 0x7fffu + ((u >> 16) & 1u);   // round-to-nearest-even
    return (unsigned short)(u >> 16);
}

// XOR swizzles (swzA: 256B rows; swzB: 128B rows)
__device__ inline int swzA(int row, int col) {
    int byteoff = (row << 8) + ((col >> 3) << 4);
    byteoff ^= (row & 7) << 4;
    return (byteoff >> 1) + (col & 7);
}
__device__ inline int swzB(int row, int col) {
    int byteoff = (row << 7) + ((col >> 3) << 4);
    byteoff ^= (row & 7) << 4;
    return (byteoff >> 1) + (col & 7);
}

// ---------------------------------------------------------------------------
// prep: V fp32 -> VT (b,d,k) bf16; mask -> additive fp32 (0/-inf).
// (Q/K conversion moved into fused8 — same f2bf, bit-identical values.)
// ---------------------------------------------------------------------------
__global__ __launch_bounds__(256) void prep_kernel(
    const float* __restrict__ V, const int* __restrict__ mask,
    unsigned short* __restrict__ VT, float* __restrict__ maskAdd)
{
    __shared__ unsigned short tile[64 * 136];
    int b = blockIdx.y, k0 = blockIdx.x << 6;
    int t = threadIdx.x;
    const size_t base = ((size_t)b * SS + k0) * DD;   // 8192 elements

    if (t < 64)
        maskAdd[(size_t)b * SS + k0 + t] =
            mask[(size_t)b * SS + k0 + t] ? 0.0f : __int_as_float(0xff800000);

    for (int i = 0; i < 8; ++i) {
        int f4 = (i << 8) + t;
        int k  = f4 >> 5;
        int n  = (f4 & 31) << 2;
        f32x4 v = reinterpret_cast<const f32x4*>(V + base)[f4];
        us4 h;
        for (int j = 0; j < 4; ++j) h[j] = f2bf(v[j]);
        *reinterpret_cast<us4*>(&tile[k * 136 + n]) = h;
    }
    __syncthreads();
    unsigned short* outp = VT + (size_t)b * DD * SS;
    for (int i = 0; i < 4; ++i) {
        int id = (i << 8) + t;
        int n  = id >> 3;
        int c8 = id & 7;
        us8 o;
        for (int j = 0; j < 8; ++j) o[j] = tile[((c8 << 3) + j) * 136 + n];
        *reinterpret_cast<us8*>(&outp[(size_t)n * SS + k0 + (c8 << 3)]) = o;
    }
}

// ---------------------------------------------------------------------------
// fused8: block = (b, 128 q-rows), full KV. 512 thr = 8 waves in 4x2 (wq,wkv).
// grid 256 (1 block/CU, XCD batch-grouped). Q/K read as fp32 and converted
// in-register (f2bf) during fragment load / staging — bit-identical to the
// old prep path. Pass A: quadrant flash; epilogue cross-wave reduce; pass B:
// bit-identical S recompute, stream P.
// ---------------------------------------------------------------------------
__global__ __launch_bounds__(512, 2) void fused8_kernel(
    const float* __restrict__ Qf, const float* __restrict__ Kf,
    const unsigned short* __restrict__ VT, const float* __restrict__ maskAdd,
    float* __restrict__ O, float* __restrict__ P)
{
    __shared__ unsigned short Ks[2][64 * 128];    // 32 KB (reused as xch floats)
    __shared__ unsigned short VTs[2][128 * 64];   // 32 KB
    __shared__ unsigned short Ps[8 * 1024];       // 16 KB: per-wave 16r x 64c
    __shared__ float Lhalf[4][32];
    __shared__ float Larr[128];

    const int id = blockIdx.x;                    // grid 256
    const int xcd = id & 7, j = id >> 3;          // j in 0..31
    const int b   = (xcd << 1) | (j >> 4);
    const int q0  = (j & 15) << 7;                // 128-row q panel

    const int t = threadIdx.x, lane = t & 63, w = t >> 6;
    const int wq = w >> 1, wkv = w & 1;
    const int lr = lane & 15, lg = lane >> 4;

    const float* Kbb = Kf + (size_t)b * SS * DD;
    const unsigned short* Vbb = VT + (size_t)b * DD * SS;
    const float* Mb = maskAdd + (size_t)b * SS;

    // Pass-A Q fragments (B-operand): q = q0 + wq*32 + m*16 + lr  (fp32->bf16)
    const float* Qp = Qf + ((size_t)b * SS + q0 + wq * 32) * DD;
    short8 qf[2][4];
    for (int m = 0; m < 2; ++m)
        for (int kb = 0; kb < 4; ++kb) {
            const float* p = Qp + (size_t)(m * 16 + lr) * DD + kb * 32 + lg * 8;
            f32x4 a0 = *reinterpret_cast<const f32x4*>(p);
            f32x4 a1 = *(reinterpret_cast<const f32x4*>(p) + 1);
            short8 s;
            for (int jj = 0; jj < 4; ++jj) { s[jj] = (short)f2bf(a0[jj]); s[4 + jj] = (short)f2bf(a1[jj]); }
            qf[m][kb] = s;
        }

    f32x4 oacc[2][8] = {};
    float rsum[2] = {0.f, 0.f};
    unsigned short* Pw = &Ps[w * 1024];

    f32x4 kstgF[2][2];
    us8 vstg[2];
#define LOADTILE(kv)                                                             \
    for (int i = 0; i < 2; ++i) {                                                \
        int f = i * 512 + t;                                                     \
        const float* kp = Kbb + (size_t)((kv) + (f >> 4)) * DD + ((f & 15) << 3);\
        kstgF[i][0] = *reinterpret_cast<const f32x4*>(kp);                       \
        kstgF[i][1] = *(reinterpret_cast<const f32x4*>(kp) + 1);                 \
        vstg[i] = *reinterpret_cast<const us8*>(                                 \
            Vbb + (size_t)(f >> 3) * SS + (kv) + ((f & 7) << 3));                \
    }
#define WRITETILE(bf)                                                            \
    for (int i = 0; i < 2; ++i) {                                                \
        int f = i * 512 + t;                                                     \
        us8 kh;                                                                  \
        for (int jj = 0; jj < 4; ++jj) {                                         \
            kh[jj]     = f2bf(kstgF[i][0][jj]);                                  \
            kh[4 + jj] = f2bf(kstgF[i][1][jj]);                                  \
        }                                                                        \
        *reinterpret_cast<us8*>(&Ks[bf][swzA(f >> 4, (f & 15) << 3)]) = kh;      \
        *reinterpret_cast<us8*>(&VTs[bf][swzB(f >> 3, (f & 7) << 3)]) = vstg[i]; \
    }
#define LOADK(kv)                                                                \
    for (int i = 0; i < 2; ++i) {                                                \
        int f = i * 512 + t;                                                     \
        const float* kp = Kbb + (size_t)((kv) + (f >> 4)) * DD + ((f & 15) << 3);\
        kstgF[i][0] = *reinterpret_cast<const f32x4*>(kp);                       \
        kstgF[i][1] = *(reinterpret_cast<const f32x4*>(kp) + 1);                 \
    }
#define WRITEK(bf)                                                               \
    for (int i = 0; i < 2; ++i) {                                                \
        int f = i * 512 + t;                                                     \
        us8 kh;                                                                  \
        for (int jj = 0; jj < 4; ++jj) {                                         \
            kh[jj]     = f2bf(kstgF[i][0][jj]);                                  \
            kh[4 + jj] = f2bf(kstgF[i][1][jj]);                                  \
        }                                                                        \
        *reinterpret_cast<us8*>(&Ks[bf][swzA(f >> 4, (f & 15) << 3)]) = kh;      \
    }

    // ---------------- pass A ----------------
    LOADTILE(0);
    WRITETILE(0);

    for (int kt = 0; kt < 32; ++kt) {
        const int cur = kt & 1;
        const int kv0 = kt << 6;
        if (kt + 1 < 32) { LOADTILE(kv0 + 64); }   // T14
        __syncthreads();                           // buf[cur] visible

        // S^T quadrant: rows kv = wkv*32 + n*16 + lg*4 + r, cols q = m*16+lr
        f32x4 sacc[2][2] = {};
        __builtin_amdgcn_s_setprio(1);
        for (int kb = 0; kb < 4; ++kb) {
            short8 kf[2];
            for (int n = 0; n < 2; ++n)
                kf[n] = *reinterpret_cast<const short8*>(
                    &Ks[cur][swzA(wkv * 32 + n * 16 + lr, kb * 32 + lg * 8)]);
            for (int n = 0; n < 2; ++n)
                for (int m = 0; m < 2; ++m)
                    sacc[m][n] = __builtin_amdgcn_mfma_f32_16x16x32_bf16(
                        kf[n], qf[m][kb], sacc[m][n], 0, 0, 0);
        }
        __builtin_amdgcn_s_setprio(0);

        // p = 2^(s*CE + ma); rowsum; stash P[q=m*16+lr][kv_local] at (lr, m*32+kv)
        for (int n = 0; n < 2; ++n) {
            f32x4 ma = *reinterpret_cast<const f32x4*>(
                Mb + kv0 + wkv * 32 + n * 16 + lg * 4);
            for (int m = 0; m < 2; ++m) {
                us4 hh;
                for (int r = 0; r < 4; ++r) {
                    float p = __builtin_amdgcn_exp2f(fmaf(sacc[m][n][r], CE, ma[r]));
                    rsum[m] += p;
                    hh[r] = f2bf(p);
                }
                *reinterpret_cast<us4*>(&Pw[swzB(lr, m * 32 + n * 16 + lg * 4)]) = hh;
            }
        }
        asm volatile("s_waitcnt lgkmcnt(0)" ::: "memory");
        __builtin_amdgcn_sched_barrier(0);

        // PV over the 32-kv quadrant (single K=32 step)
        short8 pf[2];
        for (int m = 0; m < 2; ++m)
            pf[m] = *reinterpret_cast<const short8*>(&Pw[swzB(lr, m * 32 + lg * 8)]);
        __builtin_amdgcn_s_setprio(1);
        for (int nd = 0; nd < 8; ++nd) {
            short8 vf = *reinterpret_cast<const short8*>(
                &VTs[cur][swzB(nd * 16 + lr, wkv * 32 + lg * 8)]);
            for (int m = 0; m < 2; ++m)
                oacc[m][nd] = __builtin_amdgcn_mfma_f32_16x16x32_bf16(
                    pf[m], vf, oacc[m][nd], 0, 0, 0);
        }
        __builtin_amdgcn_s_setprio(0);

        if (kt + 1 < 32) { WRITETILE(cur ^ 1); }   // readers passed top barrier
    }

    // ---------------- epilogue: cross-wave reduce + O write ----------------
    for (int m = 0; m < 2; ++m) {   // sum over lg groups (q = ... + lr)
        rsum[m] += __shfl_xor(rsum[m], 16, 64);
        rsum[m] += __shfl_xor(rsum[m], 32, 64);
    }
    __syncthreads();   // pass A fully done; Ks reusable as xch
    if (wkv == 1 && lg == 0)
        for (int m = 0; m < 2; ++m) Lhalf[wq][m * 16 + lr] = rsum[m];
    __syncthreads();
    if (wkv == 0) {
        for (int m = 0; m < 2; ++m) {
            float L = rsum[m] + Lhalf[wq][m * 16 + lr];
            if (lg == 0) Larr[wq * 32 + m * 16 + lr] = L;
        }
    }
    // oacc exchange in 2 rounds through the Ks region (32 KB = 8192 floats)
    float* xch = reinterpret_cast<float*>(&Ks[0][0]);
    for (int round = 0; round < 2; ++round) {
        __syncthreads();
        if (wkv == 1 && (wq >> 1) == round)
            for (int m = 0; m < 2; ++m)
                for (int nd = 0; nd < 8; ++nd)
                    for (int r = 0; r < 4; ++r)
                        xch[(wq & 1) * 4096 + (m * 16 + lg * 4 + r) * 128 + nd * 16 + lr]
                            = oacc[m][nd][r];
        __syncthreads();
        if (wkv == 0 && (wq >> 1) == round)
            for (int m = 0; m < 2; ++m)
                for (int nd = 0; nd < 8; ++nd)
                    for (int r = 0; r < 4; ++r)
                        oacc[m][nd][r] +=
                            xch[(wq & 1) * 4096 + (m * 16 + lg * 4 + r) * 128 + nd * 16 + lr];
    }
    __syncthreads();   // Larr + exchange complete
    if (wkv == 0) {
        float* Og = O + ((size_t)b * SS + q0 + wq * 32) * DD;
        float inv[2][4];
        for (int m = 0; m < 2; ++m)
            for (int r = 0; r < 4; ++r) {
                float L = Larr[wq * 32 + m * 16 + lg * 4 + r];
                inv[m][r] = L > 0.f ? 1.f / L : 0.f;
            }
        for (int m = 0; m < 2; ++m)
            for (int nd = 0; nd < 8; ++nd)
                for (int r = 0; r < 4; ++r)
                    Og[(size_t)(m * 16 + lg * 4 + r) * DD + nd * 16 + lr]
                        = oacc[m][nd][r] * inv[m][r];
    }
    __syncthreads();

    // pass-B per-row lil (q = w*16 + lr)
    float Lq = Larr[w * 16 + lr];
    const float lil = Lq > 0.f ? -__builtin_amdgcn_logf(Lq)
                               : __int_as_float(0xff800000);
    short8 qf2[4];
    {
        const float* Qp2 = Qf + ((size_t)b * SS + q0 + w * 16 + lr) * DD;
        for (int kb = 0; kb < 4; ++kb) {
            const float* p = Qp2 + kb * 32 + lg * 8;
            f32x4 a0 = *reinterpret_cast<const f32x4*>(p);
            f32x4 a1 = *(reinterpret_cast<const f32x4*>(p) + 1);
            short8 s;
            for (int jj = 0; jj < 4; ++jj) { s[jj] = (short)f2bf(a0[jj]); s[4 + jj] = (short)f2bf(a1[jj]); }
            qf2[kb] = s;
        }
    }

    // ---------------- pass B ----------------
    LOADK(0);
    WRITEK(0);   // safe: all exchange reads done before last barrier

    for (int kt = 0; kt < 32; ++kt) {
        const int cur = kt & 1;
        const int kv0 = kt << 6;
        if (kt + 1 < 32) { LOADK(kv0 + 64); }
        __syncthreads();

        // identical per-(q,kv) kb-chain as pass A -> bit-identical S
        f32x4 sacc2[4] = {};
        for (int kb = 0; kb < 4; ++kb) {
            short8 kf[4];
            for (int n = 0; n < 4; ++n)
                kf[n] = *reinterpret_cast<const short8*>(
                    &Ks[cur][swzA(n * 16 + lr, kb * 32 + lg * 8)]);
            for (int n = 0; n < 4; ++n)
                sacc2[n] = __builtin_amdgcn_mfma_f32_16x16x32_bf16(
                    kf[n], qf2[kb], sacc2[n], 0, 0, 0);
        }

        float* Pp = P + ((size_t)b * SS + q0 + w * 16 + lr) * SS + kv0;
        for (int n = 0; n < 4; ++n) {
            f32x4 ma = *reinterpret_cast<const f32x4*>(Mb + kv0 + n * 16 + lg * 4);
            f32x4 out;
            for (int r = 0; r < 4; ++r)
                out[r] = __builtin_amdgcn_exp2f(fmaf(sacc2[n][r], CE, ma[r]) + lil);
            *reinterpret_cast<f32x4*>(Pp + n * 16 + lg * 4) = out;
        }

        if (kt + 1 < 32) { WRITEK(cur ^ 1); }
    }
#undef LOADTILE
#undef WRITETILE
#undef LOADK
#undef WRITEK
}

// ---------------------------------------------------------------------------
// Fallback pipeline (no workspace requirements)
// ---------------------------------------------------------------------------
__global__ __launch_bounds__(256) void qk_exp_kernel(
    const float* __restrict__ Q, const float* __restrict__ Kin,
    const int* __restrict__ mask, float* __restrict__ P)
{
    __shared__ unsigned short Qs[128 * 128];
    __shared__ unsigned short Ks[128 * 128];
    const int b  = blockIdx.z;
    const int m0 = blockIdx.y << 7;
    const int n0 = blockIdx.x << 7;
    const int t  = threadIdx.x;
    const float* Qp = Q   + ((size_t)b * SS + m0) * DD;
    const float* Kp = Kin + ((size_t)b * SS + n0) * DD;
    for (int i = 0; i < 16; ++i) {
        int f4  = (i << 8) + t;
        int row = f4 >> 5;
        int col = (f4 & 31) << 2;
        f32x4 q = reinterpret_cast<const f32x4*>(Qp)[f4];
        f32x4 k = reinterpret_cast<const f32x4*>(Kp)[f4];
        us4 qh, kh;
        for (int jj = 0; jj < 4; ++jj) { qh[jj] = f2bf(q[jj]); kh[jj] = f2bf(k[jj]); }
        *reinterpret_cast<us4*>(&Qs[swzA(row, col)]) = qh;
        *reinterpret_cast<us4*>(&Ks[swzA(row, col)]) = kh;
    }
    __syncthreads();
    const int lane = t & 63, wid = t >> 6;
    const int wr = wid >> 1, wc = wid & 1;
    const int lr = lane & 15, lg = lane >> 4;
    f32x4 acc[4][4] = {};
    for (int kb = 0; kb < 4; ++kb) {
        short8 a[4], bq[4];
        int kcol = (kb << 5) + (lg << 3);
        for (int m = 0; m < 4; ++m)
            a[m] = *reinterpret_cast<const short8*>(&Qs[swzA((wr << 6) + (m << 4) + lr, kcol)]);
        for (int n = 0; n < 4; ++n)
            bq[n] = *reinterpret_cast<const short8*>(&Ks[swzA((wc << 6) + (n << 4) + lr, kcol)]);
        for (int m = 0; m < 4; ++m)
            for (int n = 0; n < 4; ++n)
                acc[m][n] = __builtin_amdgcn_mfma_f32_16x16x32_bf16(a[m], bq[n], acc[m][n], 0, 0, 0);
    }
    const int* am = mask + (size_t)b * SS;
    for (int n = 0; n < 4; ++n) {
        int col = n0 + (wc << 6) + (n << 4) + lr;
        bool allow = am[col] != 0;
        for (int m = 0; m < 4; ++m) {
            int rowb = m0 + (wr << 6) + (m << 4) + (lg << 2);
            float* Pp = P + ((size_t)b * SS + rowb) * SS + col;
            for (int r = 0; r < 4; ++r) {
                float p = allow ? __expf(acc[m][n][r] * 0.08838834764831845f) : 0.0f;
                Pp[(size_t)r * SS] = p;
            }
        }
    }
}

__global__ __launch_bounds__(256) void norm_kernel(float* __restrict__ P)
{
    int row  = (blockIdx.x << 2) + (threadIdx.x >> 6);
    int lane = threadIdx.x & 63;
    float* Pr = P + (size_t)row * SS;
    f32x4 v[8];
    float sum = 0.f;
    for (int i = 0; i < 8; ++i) {
        v[i] = reinterpret_cast<f32x4*>(Pr)[(i << 6) + lane];
        sum += v[i][0] + v[i][1] + v[i][2] + v[i][3];
    }
    for (int off = 1; off < 64; off <<= 1) sum += __shfl_xor(sum, off, 64);
    float inv = sum > 0.f ? 1.f / sum : 0.f;
    for (int i = 0; i < 8; ++i) {
        f32x4 wv = v[i];
        for (int jj = 0; jj < 4; ++jj) wv[jj] *= inv;
        reinterpret_cast<f32x4*>(Pr)[(i << 6) + lane] = wv;
    }
}

__global__ __launch_bounds__(256) void pv_fallback_kernel(
    const float* __restrict__ P, const float* __restrict__ V, float* __restrict__ O)
{
    __shared__ unsigned short Ws[64 * 64];
    const int b  = blockIdx.y;
    const int m0 = blockIdx.x << 6;
    const int t  = threadIdx.x, lane = t & 63, wid = t >> 6;
    const int wr = wid >> 1, wc = wid & 1;
    const int lr = lane & 15, lg = lane >> 4;
    const float* Pg = P + ((size_t)b * SS + m0) * SS;
    f32x4 acc[2][4] = {};
    for (int k0 = 0; k0 < SS; k0 += 64) {
        __syncthreads();
        for (int i = 0; i < 4; ++i) {
            int f4  = (i << 8) + t;
            int row = f4 >> 4;
            int col = (f4 & 15) << 2;
            f32x4 wv = *reinterpret_cast<const f32x4*>(Pg + (size_t)row * SS + k0 + col);
            us4 h;
            for (int jj = 0; jj < 4; ++jj) h[jj] = f2bf(wv[jj]);
            *reinterpret_cast<us4*>(&Ws[swzB(row, col)]) = h;
        }
        __syncthreads();
        for (int kk = 0; kk < 64; kk += 32) {
            short8 a[2], bv[4];
            int kcol = kk + (lg << 3);
            for (int m = 0; m < 2; ++m)
                a[m] = *reinterpret_cast<const short8*>(&Ws[swzB((wr << 5) + (m << 4) + lr, kcol)]);
            for (int n = 0; n < 4; ++n) {
                int col = (wc << 6) + (n << 4) + lr;
                const float* vp = V + ((size_t)b * SS + k0 + kcol) * DD + col;
                short8 x;
                for (int jj = 0; jj < 8; ++jj) x[jj] = (short)f2bf(vp[(size_t)jj * DD]);
                bv[n] = x;
            }
            for (int m = 0; m < 2; ++m)
                for (int n = 0; n < 4; ++n)
                    acc[m][n] = __builtin_amdgcn_mfma_f32_16x16x32_bf16(a[m], bv[n], acc[m][n], 0, 0, 0);
        }
    }
    float* Og = O + ((size_t)b * SS + m0) * DD;
    for (int m = 0; m < 2; ++m)
        for (int n = 0; n < 4; ++n)
            for (int r = 0; r < 4; ++r)
                Og[(size_t)((wr << 5) + (m << 4) + (lg << 2) + r) * DD
                   + (wc << 6) + (n << 4) + lr] = acc[m][n][r];
}

// ---------------------------------------------------------------------------
extern "C" void kernel_launch(void* const* d_in, const int* in_sizes, int n_in,
                              void* d_out, int out_size, void* d_ws, size_t ws_size,
                              hipStream_t stream)
{
    const float* Q  = (const float*)d_in[0];
    const float* K  = (const float*)d_in[1];
    const float* V  = (const float*)d_in[2];
    const int* mask = (const int*)d_in[3];
    float* O = (float*)d_out;
    float* P = O + (size_t)BB * SS * DD;

    const size_t nE = (size_t)BB * SS * DD;   // 4194304 elements per tensor
    const size_t need = nE * sizeof(unsigned short)
                      + (size_t)BB * SS * sizeof(float) + 256;

    if (ws_size >= need) {
        unsigned short* VT = (unsigned short*)d_ws;
        float* maskAdd = (float*)(VT + nE);

        prep_kernel<<<dim3(SS / 64, BB), 256, 0, stream>>>(V, mask, VT, maskAdd);
        fused8_kernel<<<256, 512, 0, stream>>>(Q, K, VT, maskAdd, O, P);
    } else {
        qk_exp_kernel<<<dim3(SS / 128, SS / 128, BB), 256, 0, stream>>>(Q, K, mask, P);
        norm_kernel<<<(BB * SS) / 4, 256, 0, stream>>>(P);
        pv_fallback_kernel<<<dim3(SS / 64, BB), 256, 0, stream>>>(P, V, O);
    }
}

// Round 14
// 129.616 us; speedup vs baseline: 1.7849x; 1.0310x over previous
//
#include <hip/hip_runtime.h>

#define BB 16
#define SS 2048
#define DD 128
// exp(s/sqrt(128)) = 2^(s * CE),  CE = log2(e)/sqrt(128)
#define CE (0.08838834764831845f * 1.4426950408889634f)

typedef __attribute__((ext_vector_type(4))) float f32x4;
typedef __attribute__((ext_vector_type(8))) short short8;
typedef __attribute__((ext_vector_type(4))) unsigned short us4;
typedef __attribute__((ext_vector_type(8))) unsigned short us8;

__device__ inline unsigned short f2bf(float f) {
    unsigned u = __float_as_uint(f);
    u += 0x7fffu + ((u >> 16) & 1u);   // round-to-nearest-even
    return (unsigned short)(u >> 16);
}

// XOR swizzles (swzA: 256B rows; swzB: 128B rows)
__device__ inline int swzA(int row, int col) {
    int byteoff = (row << 8) + ((col >> 3) << 4);
    byteoff ^= (row & 7) << 4;
    return (byteoff >> 1) + (col & 7);
}
__device__ inline int swzB(int row, int col) {
    int byteoff = (row << 7) + ((col >> 3) << 4);
    byteoff ^= (row & 7) << 4;
    return (byteoff >> 1) + (col & 7);
}

// ---------------------------------------------------------------------------
// prep: K fp32 -> bf16 Kb; V fp32 -> VT (b,d,k) bf16; mask -> additive fp32.
// (Q stays fp32; converted in fused8 at fragment load — read once per pass,
//  no staging amplification. K must be bf16: it is staged 64x per block.)
// ---------------------------------------------------------------------------
__global__ __launch_bounds__(256) void prep_kernel(
    const float* __restrict__ K, const float* __restrict__ V,
    const int* __restrict__ mask,
    unsigned short* __restrict__ Kb, unsigned short* __restrict__ VT,
    float* __restrict__ maskAdd)
{
    __shared__ unsigned short tile[64 * 136];
    int b = blockIdx.y, k0 = blockIdx.x << 6;
    int t = threadIdx.x;
    const size_t base = ((size_t)b * SS + k0) * DD;   // 8192 elements

    // K convert (contiguous)
    for (int i = 0; i < 8; ++i) {
        int f4 = (i << 8) + t;
        f32x4 k = reinterpret_cast<const f32x4*>(K + base)[f4];
        us4 kh;
        for (int j = 0; j < 4; ++j) kh[j] = f2bf(k[j]);
        reinterpret_cast<us4*>(Kb + base)[f4] = kh;
    }
    if (t < 64)
        maskAdd[(size_t)b * SS + k0 + t] =
            mask[(size_t)b * SS + k0 + t] ? 0.0f : __int_as_float(0xff800000);

    // V transpose
    for (int i = 0; i < 8; ++i) {
        int f4 = (i << 8) + t;
        int k  = f4 >> 5;
        int n  = (f4 & 31) << 2;
        f32x4 v = reinterpret_cast<const f32x4*>(V + base)[f4];
        us4 h;
        for (int j = 0; j < 4; ++j) h[j] = f2bf(v[j]);
        *reinterpret_cast<us4*>(&tile[k * 136 + n]) = h;
    }
    __syncthreads();
    unsigned short* outp = VT + (size_t)b * DD * SS;
    for (int i = 0; i < 4; ++i) {
        int id = (i << 8) + t;
        int n  = id >> 3;
        int c8 = id & 7;
        us8 o;
        for (int j = 0; j < 8; ++j) o[j] = tile[((c8 << 3) + j) * 136 + n];
        *reinterpret_cast<us8*>(&outp[(size_t)n * SS + k0 + (c8 << 3)]) = o;
    }
}

// ---------------------------------------------------------------------------
// fused8: block = (b, 128 q-rows), full KV. 512 thr = 8 waves in 4x2 (wq,wkv).
// grid 256 (1 block/CU, XCD batch-grouped). Q read fp32 + f2bf at load;
// K staged bf16 from Kb. Pass A: quadrant flash; epilogue cross-wave reduce;
// pass B: bit-identical S recompute, stream P.
// ---------------------------------------------------------------------------
__global__ __launch_bounds__(512, 2) void fused8_kernel(
    const float* __restrict__ Qf, const unsigned short* __restrict__ Kb,
    const unsigned short* __restrict__ VT, const float* __restrict__ maskAdd,
    float* __restrict__ O, float* __restrict__ P)
{
    __shared__ unsigned short Ks[2][64 * 128];    // 32 KB (reused as xch floats)
    __shared__ unsigned short VTs[2][128 * 64];   // 32 KB
    __shared__ unsigned short Ps[8 * 1024];       // 16 KB: per-wave 16r x 64c
    __shared__ float Lhalf[4][32];
    __shared__ float Larr[128];

    const int id = blockIdx.x;                    // grid 256
    const int xcd = id & 7, j = id >> 3;          // j in 0..31
    const int b   = (xcd << 1) | (j >> 4);
    const int q0  = (j & 15) << 7;                // 128-row q panel

    const int t = threadIdx.x, lane = t & 63, w = t >> 6;
    const int wq = w >> 1, wkv = w & 1;
    const int lr = lane & 15, lg = lane >> 4;

    const unsigned short* Kbb = Kb + (size_t)b * SS * DD;
    const unsigned short* Vbb = VT + (size_t)b * DD * SS;
    const float* Mb = maskAdd + (size_t)b * SS;

    // Pass-A Q fragments (B-operand): q = q0 + wq*32 + m*16 + lr  (fp32->bf16)
    const float* Qp = Qf + ((size_t)b * SS + q0 + wq * 32) * DD;
    short8 qf[2][4];
    for (int m = 0; m < 2; ++m)
        for (int kb = 0; kb < 4; ++kb) {
            const float* p = Qp + (size_t)(m * 16 + lr) * DD + kb * 32 + lg * 8;
            f32x4 a0 = *reinterpret_cast<const f32x4*>(p);
            f32x4 a1 = *(reinterpret_cast<const f32x4*>(p) + 1);
            short8 s;
            for (int jj = 0; jj < 4; ++jj) { s[jj] = (short)f2bf(a0[jj]); s[4 + jj] = (short)f2bf(a1[jj]); }
            qf[m][kb] = s;
        }

    f32x4 oacc[2][8] = {};
    float rsum[2] = {0.f, 0.f};
    unsigned short* Pw = &Ps[w * 1024];

    us8 kstg[2], vstg[2];
#define LOADTILE(kv)                                                             \
    for (int i = 0; i < 2; ++i) {                                                \
        int f = i * 512 + t;                                                     \
        kstg[i] = *reinterpret_cast<const us8*>(                                 \
            Kbb + (size_t)((kv) + (f >> 4)) * DD + ((f & 15) << 3));             \
        vstg[i] = *reinterpret_cast<const us8*>(                                 \
            Vbb + (size_t)(f >> 3) * SS + (kv) + ((f & 7) << 3));                \
    }
#define WRITETILE(bf)                                                            \
    for (int i = 0; i < 2; ++i) {                                                \
        int f = i * 512 + t;                                                     \
        *reinterpret_cast<us8*>(&Ks[bf][swzA(f >> 4, (f & 15) << 3)]) = kstg[i]; \
        *reinterpret_cast<us8*>(&VTs[bf][swzB(f >> 3, (f & 7) << 3)]) = vstg[i]; \
    }
#define LOADK(kv)                                                                \
    for (int i = 0; i < 2; ++i) {                                                \
        int f = i * 512 + t;                                                     \
        kstg[i] = *reinterpret_cast<const us8*>(                                 \
            Kbb + (size_t)((kv) + (f >> 4)) * DD + ((f & 15) << 3));             \
    }
#define WRITEK(bf)                                                               \
    for (int i = 0; i < 2; ++i) {                                                \
        int f = i * 512 + t;                                                     \
        *reinterpret_cast<us8*>(&Ks[bf][swzA(f >> 4, (f & 15) << 3)]) = kstg[i]; \
    }

    // ---------------- pass A ----------------
    LOADTILE(0);
    WRITETILE(0);

    for (int kt = 0; kt < 32; ++kt) {
        const int cur = kt & 1;
        const int kv0 = kt << 6;
        if (kt + 1 < 32) { LOADTILE(kv0 + 64); }   // T14
        __syncthreads();                           // buf[cur] visible

        // S^T quadrant: rows kv = wkv*32 + n*16 + lg*4 + r, cols q = m*16+lr
        f32x4 sacc[2][2] = {};
        __builtin_amdgcn_s_setprio(1);
        for (int kb = 0; kb < 4; ++kb) {
            short8 kf[2];
            for (int n = 0; n < 2; ++n)
                kf[n] = *reinterpret_cast<const short8*>(
                    &Ks[cur][swzA(wkv * 32 + n * 16 + lr, kb * 32 + lg * 8)]);
            for (int n = 0; n < 2; ++n)
                for (int m = 0; m < 2; ++m)
                    sacc[m][n] = __builtin_amdgcn_mfma_f32_16x16x32_bf16(
                        kf[n], qf[m][kb], sacc[m][n], 0, 0, 0);
        }
        __builtin_amdgcn_s_setprio(0);

        // p = 2^(s*CE + ma); rowsum; stash P[q=m*16+lr][kv_local] at (lr, m*32+kv)
        for (int n = 0; n < 2; ++n) {
            f32x4 ma = *reinterpret_cast<const f32x4*>(
                Mb + kv0 + wkv * 32 + n * 16 + lg * 4);
            for (int m = 0; m < 2; ++m) {
                us4 hh;
                for (int r = 0; r < 4; ++r) {
                    float p = __builtin_amdgcn_exp2f(fmaf(sacc[m][n][r], CE, ma[r]));
                    rsum[m] += p;
                    hh[r] = f2bf(p);
                }
                *reinterpret_cast<us4*>(&Pw[swzB(lr, m * 32 + n * 16 + lg * 4)]) = hh;
            }
        }
        asm volatile("s_waitcnt lgkmcnt(0)" ::: "memory");
        __builtin_amdgcn_sched_barrier(0);

        // PV over the 32-kv quadrant (single K=32 step)
        short8 pf[2];
        for (int m = 0; m < 2; ++m)
            pf[m] = *reinterpret_cast<const short8*>(&Pw[swzB(lr, m * 32 + lg * 8)]);
        __builtin_amdgcn_s_setprio(1);
        for (int nd = 0; nd < 8; ++nd) {
            short8 vf = *reinterpret_cast<const short8*>(
                &VTs[cur][swzB(nd * 16 + lr, wkv * 32 + lg * 8)]);
            for (int m = 0; m < 2; ++m)
                oacc[m][nd] = __builtin_amdgcn_mfma_f32_16x16x32_bf16(
                    pf[m], vf, oacc[m][nd], 0, 0, 0);
        }
        __builtin_amdgcn_s_setprio(0);

        if (kt + 1 < 32) { WRITETILE(cur ^ 1); }   // readers passed top barrier
    }

    // ---------------- epilogue: cross-wave reduce + O write ----------------
    for (int m = 0; m < 2; ++m) {   // sum over lg groups (q = ... + lr)
        rsum[m] += __shfl_xor(rsum[m], 16, 64);
        rsum[m] += __shfl_xor(rsum[m], 32, 64);
    }
    __syncthreads();   // pass A fully done; Ks reusable as xch
    if (wkv == 1 && lg == 0)
        for (int m = 0; m < 2; ++m) Lhalf[wq][m * 16 + lr] = rsum[m];
    __syncthreads();
    if (wkv == 0) {
        for (int m = 0; m < 2; ++m) {
            float L = rsum[m] + Lhalf[wq][m * 16 + lr];
            if (lg == 0) Larr[wq * 32 + m * 16 + lr] = L;
        }
    }
    // oacc exchange in 2 rounds through the Ks region (32 KB = 8192 floats)
    float* xch = reinterpret_cast<float*>(&Ks[0][0]);
    for (int round = 0; round < 2; ++round) {
        __syncthreads();
        if (wkv == 1 && (wq >> 1) == round)
            for (int m = 0; m < 2; ++m)
                for (int nd = 0; nd < 8; ++nd)
                    for (int r = 0; r < 4; ++r)
                        xch[(wq & 1) * 4096 + (m * 16 + lg * 4 + r) * 128 + nd * 16 + lr]
                            = oacc[m][nd][r];
        __syncthreads();
        if (wkv == 0 && (wq >> 1) == round)
            for (int m = 0; m < 2; ++m)
                for (int nd = 0; nd < 8; ++nd)
                    for (int r = 0; r < 4; ++r)
                        oacc[m][nd][r] +=
                            xch[(wq & 1) * 4096 + (m * 16 + lg * 4 + r) * 128 + nd * 16 + lr];
    }
    __syncthreads();   // Larr + exchange complete
    if (wkv == 0) {
        float* Og = O + ((size_t)b * SS + q0 + wq * 32) * DD;
        float inv[2][4];
        for (int m = 0; m < 2; ++m)
            for (int r = 0; r < 4; ++r) {
                float L = Larr[wq * 32 + m * 16 + lg * 4 + r];
                inv[m][r] = L > 0.f ? 1.f / L : 0.f;
            }
        for (int m = 0; m < 2; ++m)
            for (int nd = 0; nd < 8; ++nd)
                for (int r = 0; r < 4; ++r)
                    Og[(size_t)(m * 16 + lg * 4 + r) * DD + nd * 16 + lr]
                        = oacc[m][nd][r] * inv[m][r];
    }
    __syncthreads();

    // pass-B per-row lil (q = w*16 + lr)
    float Lq = Larr[w * 16 + lr];
    const float lil = Lq > 0.f ? -__builtin_amdgcn_logf(Lq)
                               : __int_as_float(0xff800000);
    short8 qf2[4];
    {
        const float* Qp2 = Qf + ((size_t)b * SS + q0 + w * 16 + lr) * DD;
        for (int kb = 0; kb < 4; ++kb) {
            const float* p = Qp2 + kb * 32 + lg * 8;
            f32x4 a0 = *reinterpret_cast<const f32x4*>(p);
            f32x4 a1 = *(reinterpret_cast<const f32x4*>(p) + 1);
            short8 s;
            for (int jj = 0; jj < 4; ++jj) { s[jj] = (short)f2bf(a0[jj]); s[4 + jj] = (short)f2bf(a1[jj]); }
            qf2[kb] = s;
        }
    }

    // ---------------- pass B ----------------
    LOADK(0);
    WRITEK(0);   // safe: all exchange reads done before last barrier

    for (int kt = 0; kt < 32; ++kt) {
        const int cur = kt & 1;
        const int kv0 = kt << 6;
        if (kt + 1 < 32) { LOADK(kv0 + 64); }
        __syncthreads();

        // identical per-(q,kv) kb-chain as pass A -> bit-identical S
        f32x4 sacc2[4] = {};
        for (int kb = 0; kb < 4; ++kb) {
            short8 kf[4];
            for (int n = 0; n < 4; ++n)
                kf[n] = *reinterpret_cast<const short8*>(
                    &Ks[cur][swzA(n * 16 + lr, kb * 32 + lg * 8)]);
            for (int n = 0; n < 4; ++n)
                sacc2[n] = __builtin_amdgcn_mfma_f32_16x16x32_bf16(
                    kf[n], qf2[kb], sacc2[n], 0, 0, 0);
        }

        float* Pp = P + ((size_t)b * SS + q0 + w * 16 + lr) * SS + kv0;
        for (int n = 0; n < 4; ++n) {
            f32x4 ma = *reinterpret_cast<const f32x4*>(Mb + kv0 + n * 16 + lg * 4);
            f32x4 out;
            for (int r = 0; r < 4; ++r)
                out[r] = __builtin_amdgcn_exp2f(fmaf(sacc2[n][r], CE, ma[r]) + lil);
            *reinterpret_cast<f32x4*>(Pp + n * 16 + lg * 4) = out;
        }

        if (kt + 1 < 32) { WRITEK(cur ^ 1); }
    }
#undef LOADTILE
#undef WRITETILE
#undef LOADK
#undef WRITEK
}

// ---------------------------------------------------------------------------
// Fallback pipeline (no workspace requirements)
// ---------------------------------------------------------------------------
__global__ __launch_bounds__(256) void qk_exp_kernel(
    const float* __restrict__ Q, const float* __restrict__ Kin,
    const int* __restrict__ mask, float* __restrict__ P)
{
    __shared__ unsigned short Qs[128 * 128];
    __shared__ unsigned short Ks[128 * 128];
    const int b  = blockIdx.z;
    const int m0 = blockIdx.y << 7;
    const int n0 = blockIdx.x << 7;
    const int t  = threadIdx.x;
    const float* Qp = Q   + ((size_t)b * SS + m0) * DD;
    const float* Kp = Kin + ((size_t)b * SS + n0) * DD;
    for (int i = 0; i < 16; ++i) {
        int f4  = (i << 8) + t;
        int row = f4 >> 5;
        int col = (f4 & 31) << 2;
        f32x4 q = reinterpret_cast<const f32x4*>(Qp)[f4];
        f32x4 k = reinterpret_cast<const f32x4*>(Kp)[f4];
        us4 qh, kh;
        for (int jj = 0; jj < 4; ++jj) { qh[jj] = f2bf(q[jj]); kh[jj] = f2bf(k[jj]); }
        *reinterpret_cast<us4*>(&Qs[swzA(row, col)]) = qh;
        *reinterpret_cast<us4*>(&Ks[swzA(row, col)]) = kh;
    }
    __syncthreads();
    const int lane = t & 63, wid = t >> 6;
    const int wr = wid >> 1, wc = wid & 1;
    const int lr = lane & 15, lg = lane >> 4;
    f32x4 acc[4][4] = {};
    for (int kb = 0; kb < 4; ++kb) {
        short8 a[4], bq[4];
        int kcol = (kb << 5) + (lg << 3);
        for (int m = 0; m < 4; ++m)
            a[m] = *reinterpret_cast<const short8*>(&Qs[swzA((wr << 6) + (m << 4) + lr, kcol)]);
        for (int n = 0; n < 4; ++n)
            bq[n] = *reinterpret_cast<const short8*>(&Ks[swzA((wc << 6) + (n << 4) + lr, kcol)]);
        for (int m = 0; m < 4; ++m)
            for (int n = 0; n < 4; ++n)
                acc[m][n] = __builtin_amdgcn_mfma_f32_16x16x32_bf16(a[m], bq[n], acc[m][n], 0, 0, 0);
    }
    const int* am = mask + (size_t)b * SS;
    for (int n = 0; n < 4; ++n) {
        int col = n0 + (wc << 6) + (n << 4) + lr;
        bool allow = am[col] != 0;
        for (int m = 0; m < 4; ++m) {
            int rowb = m0 + (wr << 6) + (m << 4) + (lg << 2);
            float* Pp = P + ((size_t)b * SS + rowb) * SS + col;
            for (int r = 0; r < 4; ++r) {
                float p = allow ? __expf(acc[m][n][r] * 0.08838834764831845f) : 0.0f;
                Pp[(size_t)r * SS] = p;
            }
        }
    }
}

__global__ __launch_bounds__(256) void norm_kernel(float* __restrict__ P)
{
    int row  = (blockIdx.x << 2) + (threadIdx.x >> 6);
    int lane = threadIdx.x & 63;
    float* Pr = P + (size_t)row * SS;
    f32x4 v[8];
    float sum = 0.f;
    for (int i = 0; i < 8; ++i) {
        v[i] = reinterpret_cast<f32x4*>(Pr)[(i << 6) + lane];
        sum += v[i][0] + v[i][1] + v[i][2] + v[i][3];
    }
    for (int off = 1; off < 64; off <<= 1) sum += __shfl_xor(sum, off, 64);
    float inv = sum > 0.f ? 1.f / sum : 0.f;
    for (int i = 0; i < 8; ++i) {
        f32x4 wv = v[i];
        for (int jj = 0; jj < 4; ++jj) wv[jj] *= inv;
        reinterpret_cast<f32x4*>(Pr)[(i << 6) + lane] = wv;
    }
}

__global__ __launch_bounds__(256) void pv_fallback_kernel(
    const float* __restrict__ P, const float* __restrict__ V, float* __restrict__ O)
{
    __shared__ unsigned short Ws[64 * 64];
    const int b  = blockIdx.y;
    const int m0 = blockIdx.x << 6;
    const int t  = threadIdx.x, lane = t & 63, wid = t >> 6;
    const int wr = wid >> 1, wc = wid & 1;
    const int lr = lane & 15, lg = lane >> 4;
    const float* Pg = P + ((size_t)b * SS + m0) * SS;
    f32x4 acc[2][4] = {};
    for (int k0 = 0; k0 < SS; k0 += 64) {
        __syncthreads();
        for (int i = 0; i < 4; ++i) {
            int f4  = (i << 8) + t;
            int row = f4 >> 4;
            int col = (f4 & 15) << 2;
            f32x4 wv = *reinterpret_cast<const f32x4*>(Pg + (size_t)row * SS + k0 + col);
            us4 h;
            for (int jj = 0; jj < 4; ++jj) h[jj] = f2bf(wv[jj]);
            *reinterpret_cast<us4*>(&Ws[swzB(row, col)]) = h;
        }
        __syncthreads();
        for (int kk = 0; kk < 64; kk += 32) {
            short8 a[2], bv[4];
            int kcol = kk + (lg << 3);
            for (int m = 0; m < 2; ++m)
                a[m] = *reinterpret_cast<const short8*>(&Ws[swzB((wr << 5) + (m << 4) + lr, kcol)]);
            for (int n = 0; n < 4; ++n) {
                int col = (wc << 6) + (n << 4) + lr;
                const float* vp = V + ((size_t)b * SS + k0 + kcol) * DD + col;
                short8 x;
                for (int jj = 0; jj < 8; ++jj) x[jj] = (short)f2bf(vp[(size_t)jj * DD]);
                bv[n] = x;
            }
            for (int m = 0; m < 2; ++m)
                for (int n = 0; n < 4; ++n)
                    acc[m][n] = __builtin_amdgcn_mfma_f32_16x16x32_bf16(a[m], bv[n], acc[m][n], 0, 0, 0);
        }
    }
    float* Og = O + ((size_t)b * SS + m0) * DD;
    for (int m = 0; m < 2; ++m)
        for (int n = 0; n < 4; ++n)
            for (int r = 0; r < 4; ++r)
                Og[(size_t)((wr << 5) + (m << 4) + (lg << 2) + r) * DD
                   + (wc << 6) + (n << 4) + lr] = acc[m][n][r];
}

// ---------------------------------------------------------------------------
extern "C" void kernel_launch(void* const* d_in, const int* in_sizes, int n_in,
                              void* d_out, int out_size, void* d_ws, size_t ws_size,
                              hipStream_t stream)
{
    const float* Q  = (const float*)d_in[0];
    const float* K  = (const float*)d_in[1];
    const float* V  = (const float*)d_in[2];
    const int* mask = (const int*)d_in[3];
    float* O = (float*)d_out;
    float* P = O + (size_t)BB * SS * DD;

    const size_t nE = (size_t)BB * SS * DD;   // 4194304 elements per tensor
    const size_t need = 2 * nE * sizeof(unsigned short)
                      + (size_t)BB * SS * sizeof(float) + 256;

    if (ws_size >= need) {
        unsigned short* Kb = (unsigned short*)d_ws;
        unsigned short* VT = Kb + nE;
        float* maskAdd = (float*)(VT + nE);

        prep_kernel<<<dim3(SS / 64, BB), 256, 0, stream>>>(K, V, mask, Kb, VT, maskAdd);
        fused8_kernel<<<256, 512, 0, stream>>>(Q, Kb, VT, maskAdd, O, P);
    } else {
        qk_exp_kernel<<<dim3(SS / 128, SS / 128, BB), 256, 0, stream>>>(Q, K, mask, P);
        norm_kernel<<<(BB * SS) / 4, 256, 0, stream>>>(P);
        pv_fallback_kernel<<<dim3(SS / 64, BB), 256, 0, stream>>>(P, V, O);
    }
}